// Round 3
// baseline (1147.230 us; speedup 1.0000x reference)
//
#include <hip/hip_runtime.h>
#include <math.h>

#define NN 100000
#define NE 1600000
#define H 128
#define LH 384
#define GG 512
#define CC 10
#define EPSBN 1e-5f

typedef __attribute__((ext_vector_type(4))) float f32x4;
typedef __attribute__((ext_vector_type(8))) short s16x8;
typedef unsigned long long u64;

__device__ inline ushort f2b(float f) {
    uint u = __float_as_uint(f);
    uint r = (u + 0x7FFFu + ((u >> 16) & 1u)) >> 16;
    return (ushort)r;
}
__device__ inline float b2f(ushort b) { return __uint_as_float(((uint)b) << 16); }
__device__ inline float blo(uint v) { return __uint_as_float(v << 16); }
__device__ inline float bhi(uint v) { return __uint_as_float(v & 0xFFFF0000u); }

// ---------------- W transpose + bf16 convert: WT[j*128+k] = W[k*128+j] ------

__global__ void k_wt(const float* __restrict__ W, ushort* __restrict__ WT, int nmat) {
    int mat = blockIdx.x >> 7;
    int k = blockIdx.x & 127;
    int j = threadIdx.x;  // 128 threads
    WT[(size_t)mat * H * H + j * H + k] = f2b(W[(size_t)mat * H * H + k * H + j]);
}

// ---------------- bucketed CSR build ----------------
// bucket b = dst >> 6  (64 nodes per bucket)

__global__ void k_bhist(const int* __restrict__ dst, int* __restrict__ bhist,
                        int e, int nbuck) {
    __shared__ int lh[1600];
    for (int j = threadIdx.x; j < nbuck; j += 256) lh[j] = 0;
    __syncthreads();
    int stride = gridDim.x * 256;
    for (int i = blockIdx.x * 256 + threadIdx.x; i < e; i += stride)
        atomicAdd(&lh[dst[i] >> 6], 1);
    __syncthreads();
    for (int j = threadIdx.x; j < nbuck; j += 256) {
        int v = lh[j];
        if (v) atomicAdd(&bhist[j], v);
    }
}

__global__ void k_bscan(const int* __restrict__ bhist, int* __restrict__ bbase,
                        int* __restrict__ bcursor, int nbuck) {
    __shared__ int sh[256];
    int t = threadIdx.x;
    const int per = 7;  // 256*7 = 1792 >= nbuck
    int base = t * per;
    int v[per];
    int s = 0;
    for (int j = 0; j < per; ++j) {
        int idx = base + j;
        v[j] = (idx < nbuck) ? bhist[idx] : 0;
        s += v[j];
    }
    sh[t] = s;
    __syncthreads();
    for (int off = 1; off < 256; off <<= 1) {
        int x = (t >= off) ? sh[t - off] : 0;
        __syncthreads();
        sh[t] += x;
        __syncthreads();
    }
    int run = sh[t] - s;
    for (int j = 0; j < per; ++j) {
        int idx = base + j;
        if (idx < nbuck) { bbase[idx] = run; bcursor[idx] = run; }
        run += v[j];
    }
    if (t == 255) bbase[nbuck] = run;
}

__global__ void k_bscatter(const int* __restrict__ src, const int* __restrict__ dst,
                           int* __restrict__ bcursor, u64* __restrict__ ebuf, int e) {
    int stride = gridDim.x * 256;
    for (int i = blockIdx.x * 256 + threadIdx.x; i < e; i += stride) {
        int s = src[i], d = dst[i];
        int p = atomicAdd(&bcursor[d >> 6], 1);
        ebuf[p] = ((u64)(uint)d << 32) | (uint)s;
    }
}

__global__ void k_bfinal(const u64* __restrict__ ebuf, const int* __restrict__ bbase,
                         int* __restrict__ rp, float* __restrict__ dinv,
                         int* __restrict__ col, int n, int e) {
    __shared__ int hcnt[64], hoff[64], hcur[64];
    int b = blockIdx.x;
    int t = threadIdx.x;
    int node0 = b * 64;
    int nodes = n - node0; if (nodes > 64) nodes = 64;
    int e0 = bbase[b], e1 = bbase[b + 1];
    int m = e1 - e0;
    if (t < 64) hcnt[t] = 0;
    __syncthreads();
    for (int i = t; i < m; i += 256) {
        int d = (int)(ebuf[e0 + i] >> 32);
        atomicAdd(&hcnt[d - node0], 1);
    }
    __syncthreads();
    if (t == 0) {
        int run = 0;
        for (int j = 0; j < 64; ++j) { hoff[j] = run; run += hcnt[j]; }
    }
    __syncthreads();
    if (t < nodes) {
        int node = node0 + t;
        rp[node] = e0 + hoff[t];
        dinv[node] = rsqrtf((float)(hcnt[t] + 1));
    }
    if (t < 64) hcur[t] = hoff[t];
    if (b == 0 && t == 0) rp[n] = e;
    __syncthreads();
    for (int i = t; i < m; i += 256) {
        u64 u = ebuf[e0 + i];
        int d = (int)(u >> 32) - node0;
        int s = (int)(uint)u;
        int p = atomicAdd(&hcur[d], 1);
        col[e0 + p] = s;
    }
}

// ---------------- MFMA GEMM: C[n,128]bf16 = A[n,lda] @ W[128,128] ----------
// AFP32: A is fp32 (converted during staging); else bf16.

template <int AFP32>
__global__ __launch_bounds__(256) void k_gemm(
    const void* __restrict__ Ap, int lda, const ushort* __restrict__ WT,
    ushort* __restrict__ Cout, int n) {
    __shared__ ushort As[64][136];
    __shared__ ushort Ws[128][136];
    int t = threadIdx.x;
    int wave = t >> 6, lane = t & 63;
    int rowBase = blockIdx.x * 64;

    if (AFP32) {
        const float* A = (const float*)Ap;
        for (int i = t; i < 64 * 32; i += 256) {
            int r = i >> 5, c4 = i & 31;
            int row = rowBase + r;
            float4 v = make_float4(0.f, 0.f, 0.f, 0.f);
            if (row < n) v = *(const float4*)(A + (size_t)row * lda + c4 * 4);
            ushort4 o;
            o.x = f2b(v.x); o.y = f2b(v.y); o.z = f2b(v.z); o.w = f2b(v.w);
            *(ushort4*)(&As[r][c4 * 4]) = o;
        }
    } else {
        const ushort* A = (const ushort*)Ap;
        for (int i = t; i < 64 * 16; i += 256) {
            int r = i >> 4, c8 = i & 15;
            int row = rowBase + r;
            uint4 v = make_uint4(0u, 0u, 0u, 0u);
            if (row < n) v = *(const uint4*)(A + (size_t)row * lda + c8 * 8);
            *(uint4*)(&As[r][c8 * 8]) = v;
        }
    }
    for (int i = t; i < 128 * 16; i += 256) {
        int j = i >> 4, c8 = i & 15;
        uint4 v = *(const uint4*)(WT + j * H + c8 * 8);
        *(uint4*)(&Ws[j][c8 * 8]) = v;
    }
    __syncthreads();

    int m = lane & 15, q = lane >> 4;
    f32x4 acc[8];
#pragma unroll
    for (int c = 0; c < 8; ++c) acc[c] = (f32x4){0.f, 0.f, 0.f, 0.f};
#pragma unroll
    for (int kc = 0; kc < 4; ++kc) {
        int kof = kc * 32 + q * 8;
        s16x8 afrag = *(const s16x8*)(&As[wave * 16 + m][kof]);
#pragma unroll
        for (int c = 0; c < 8; ++c) {
            s16x8 bfrag = *(const s16x8*)(&Ws[c * 16 + m][kof]);
            acc[c] = __builtin_amdgcn_mfma_f32_16x16x32_bf16(afrag, bfrag, acc[c], 0, 0, 0);
        }
    }
#pragma unroll
    for (int c = 0; c < 8; ++c) {
        int colI = c * 16 + m;
#pragma unroll
        for (int r = 0; r < 4; ++r) {
            int row = rowBase + wave * 16 + q * 4 + r;
            if (row < n) Cout[(size_t)row * H + colI] = f2b(acc[c][r]);
        }
    }
}

// ---------------- Aggregation + fused BN stats ----------------
// block = 256 (4 waves); each wave processes 8 consecutive nodes.
// out[d] = dinv[d]*(dinv[d]*hw[d] + sum_s dinv[s]*hw[s])   (bias dropped: cancels in BN)

__global__ void k_agg(const ushort* __restrict__ hwb, const int* __restrict__ rp,
                      const int* __restrict__ col, const float* __restrict__ dinv,
                      float* __restrict__ stats, ushort* __restrict__ aggb, int n) {
    __shared__ float red[4][128];
    int wave = threadIdx.x >> 6, lane = threadIdx.x & 63;
    int nodeBase = blockIdx.x * 32 + wave * 8;
    const uint* hw32 = (const uint*)hwb;
    uint* agg32 = (uint*)aggb;
    float s0 = 0.f, s1 = 0.f, q0 = 0.f, q1 = 0.f;
    for (int ni = 0; ni < 8; ++ni) {
        int node = nodeBase + ni;
        if (node >= n) break;
        float dn = dinv[node];
        uint sv = hw32[(size_t)node * 64 + lane];
        float a0 = dn * blo(sv), a1 = dn * bhi(sv);
        int p = rp[node], pe = rp[node + 1];
        for (; p + 2 <= pe; p += 2) {
            int sA = col[p], sB = col[p + 1];
            float dA = dinv[sA], dB = dinv[sB];
            uint vA = hw32[(size_t)sA * 64 + lane];
            uint vB = hw32[(size_t)sB * 64 + lane];
            a0 += dA * blo(vA) + dB * blo(vB);
            a1 += dA * bhi(vA) + dB * bhi(vB);
        }
        if (p < pe) {
            int sA = col[p];
            float dA = dinv[sA];
            uint vA = hw32[(size_t)sA * 64 + lane];
            a0 += dA * blo(vA);
            a1 += dA * bhi(vA);
        }
        float o0 = dn * a0, o1 = dn * a1;
        s0 += o0; q0 += o0 * o0;
        s1 += o1; q1 += o1 * o1;
        agg32[(size_t)node * 64 + lane] = (uint)f2b(o0) | ((uint)f2b(o1) << 16);
    }
    // cross-wave reduce: sums
    red[wave][lane * 2] = s0;
    red[wave][lane * 2 + 1] = s1;
    __syncthreads();
    if (threadIdx.x < 128) {
        int f = threadIdx.x;
        float s = red[0][f] + red[1][f] + red[2][f] + red[3][f];
        atomicAdd(&stats[f], s);
    }
    __syncthreads();
    red[wave][lane * 2] = q0;
    red[wave][lane * 2 + 1] = q1;
    __syncthreads();
    if (threadIdx.x < 128) {
        int f = threadIdx.x;
        float q = red[0][f] + red[1][f] + red[2][f] + red[3][f];
        atomicAdd(&stats[128 + f], q);
    }
}

// ---------------- BN apply + ReLU -> bf16 concat buffer ----------------

__global__ void k_bnapply(const ushort* __restrict__ aggb, const float* __restrict__ stats,
                          const float* __restrict__ g, const float* __restrict__ bt,
                          ushort* __restrict__ outp, int n, int ldo) {
    int i = blockIdx.x * blockDim.x + threadIdx.x;
    if (i >= n * H) return;
    int f = i & 127;
    int r = i >> 7;
    float inv_n = 1.0f / (float)n;
    float mu = stats[f] * inv_n;
    float var = stats[128 + f] * inv_n - mu * mu;
    float v = (b2f(aggb[i]) - mu) * rsqrtf(var + EPSBN) * g[f] + bt[f];
    outp[(size_t)r * ldo + f] = f2b(fmaxf(v, 0.f));
}

// ---------------- Pooling ----------------

__global__ void k_gcount(const int* __restrict__ batch, int* __restrict__ gcnt, int n) {
    int i = blockIdx.x * blockDim.x + threadIdx.x;
    if (i < n) atomicAdd(&gcnt[batch[i]], 1);
}

__global__ void k_gscan(const int* __restrict__ gcnt, int* __restrict__ gptr) {
    if (threadIdx.x == 0 && blockIdx.x == 0) {
        int s = 0;
        for (int g = 0; g < GG; ++g) { gptr[g] = s; s += gcnt[g]; }
        gptr[GG] = s;
    }
}

__global__ void k_pool(const ushort* __restrict__ hcat, const int* __restrict__ gptr,
                       float* __restrict__ pooled) {
    int g = blockIdx.x;
    int f = threadIdx.x;  // 384 threads
    int r0 = gptr[g], r1 = gptr[g + 1];
    float s = 0.f;
    for (int r = r0; r < r1; ++r) s += b2f(hcat[(size_t)r * LH + f]);
    float c = (float)(r1 - r0);
    pooled[g * LH + f] = s / fmaxf(c, 1.f);
}

// ---------------- MLP head ----------------

__global__ void k_mlp1(const float* __restrict__ pooled, const float* __restrict__ Wl1,
                       const float* __restrict__ bl1, float* __restrict__ z) {
    __shared__ float row[LH];
    int g = blockIdx.x;
    int j = threadIdx.x;  // 128 threads
    for (int k = j; k < LH; k += H) row[k] = pooled[g * LH + k];
    __syncthreads();
    float acc = bl1[j];
    for (int k = 0; k < LH; ++k) acc += row[k] * Wl1[k * H + j];
    z[g * H + j] = acc;
}

__global__ void k_zstats(const float* __restrict__ z, float* __restrict__ st) {
    int j = threadIdx.x;  // 128 threads, 1 block
    float s = 0.f, q = 0.f;
    for (int g = 0; g < GG; ++g) {
        float v = z[g * H + j];
        s += v;
        q += v * v;
    }
    st[j] = s;
    st[128 + j] = q;
}

__global__ void k_mlp2(const float* __restrict__ z, const float* __restrict__ st,
                       const float* __restrict__ gl, const float* __restrict__ btl,
                       const float* __restrict__ Wl2, const float* __restrict__ bl2,
                       float* __restrict__ out) {
    __shared__ float zn[H];
    __shared__ float logit[CC];
    int g = blockIdx.x;
    int t = threadIdx.x;  // 128 threads
    float mu = st[t] * (1.f / GG);
    float var = st[128 + t] * (1.f / GG) - mu * mu;
    float v = (z[g * H + t] - mu) * rsqrtf(var + EPSBN) * gl[t] + btl[t];
    zn[t] = fmaxf(v, 0.f);
    __syncthreads();
    if (t < CC) {
        float acc = bl2[t];
        for (int k = 0; k < H; ++k) acc += zn[k] * Wl2[k * CC + t];
        logit[t] = acc;
    }
    __syncthreads();
    if (t == 0) {
        float m = -1e30f;
        for (int c = 0; c < CC; ++c) m = fmaxf(m, logit[c]);
        float se = 0.f;
        for (int c = 0; c < CC; ++c) se += expf(logit[c] - m);
        float lse = m + logf(se);
        for (int c = 0; c < CC; ++c) out[g * CC + c] = logit[c] - lse;
    }
}

// ---------------- launch ----------------

extern "C" void kernel_launch(void* const* d_in, const int* in_sizes, int n_in,
                              void* d_out, int out_size, void* d_ws, size_t ws_size,
                              hipStream_t stream) {
    const float* x   = (const float*)d_in[0];
    const int*   ei  = (const int*)d_in[1];
    const int*   bat = (const int*)d_in[2];
    const float* W1  = (const float*)d_in[3];
    const float* g1  = (const float*)d_in[5];
    const float* bt1 = (const float*)d_in[6];
    const float* Wc  = (const float*)d_in[7];
    const float* gc  = (const float*)d_in[9];
    const float* btc = (const float*)d_in[10];
    const float* Wl1 = (const float*)d_in[11];
    const float* bl1 = (const float*)d_in[12];
    const float* gl  = (const float*)d_in[13];
    const float* btl = (const float*)d_in[14];
    const float* Wl2 = (const float*)d_in[15];
    const float* bl2 = (const float*)d_in[16];
    float* out = (float*)d_out;

    const int n = in_sizes[2];
    const int e = in_sizes[1] / 2;
    const int* src = ei;
    const int* dst = ei + e;
    const int nbuck = (n + 63) / 64;

    size_t off = 0;
    char* base = (char*)d_ws;
    auto take = [&](size_t nbytes) -> void* {
        void* p = base + off;
        off += (nbytes + 255) & ~(size_t)255;
        return p;
    };
    int*    rp      = (int*)take((size_t)(NN + 1) * 4);
    int*    col     = (int*)take((size_t)NE * 4);
    float*  dinv    = (float*)take((size_t)NN * 4);
    int*    bhist   = (int*)take((size_t)(nbuck + 1) * 4);
    int*    bbase   = (int*)take((size_t)(nbuck + 1) * 4);
    int*    bcursor = (int*)take((size_t)(nbuck + 1) * 4);
    u64*    ebuf    = (u64*)take((size_t)NE * 8);
    float*  stats   = (float*)take(1024);
    int*    gcnt    = (int*)take((size_t)GG * 4);
    int*    gptr    = (int*)take((size_t)(GG + 1) * 4);
    ushort* WTb     = (ushort*)take((size_t)3 * H * H * 2);
    ushort* hwb     = (ushort*)take((size_t)NN * H * 2);
    ushort* aggb    = (ushort*)take((size_t)NN * H * 2);
    ushort* hcatb   = (ushort*)take((size_t)NN * LH * 2);
    float*  pooled  = (float*)take((size_t)GG * LH * 4);
    float*  z       = (float*)take((size_t)GG * H * 4);
    float*  zst     = (float*)take(1024);

    // ---- weight transpose/convert ----
    k_wt<<<H, H, 0, stream>>>(W1, WTb, 1);
    k_wt<<<2 * H, H, 0, stream>>>(Wc, WTb + (size_t)H * H, 2);

    // ---- bucketed CSR build ----
    hipMemsetAsync(bhist, 0, (size_t)(nbuck + 1) * 4, stream);
    k_bhist<<<256, 256, 0, stream>>>(dst, bhist, e, nbuck);
    k_bscan<<<1, 256, 0, stream>>>(bhist, bbase, bcursor, nbuck);
    k_bscatter<<<512, 256, 0, stream>>>(src, dst, bcursor, ebuf, e);
    k_bfinal<<<nbuck, 256, 0, stream>>>(ebuf, bbase, rp, dinv, col, n, e);

    // ---- 3 GCN layers ----
    for (int l = 0; l < 3; ++l) {
        const float* gm  = (l == 0) ? g1 : (gc + (size_t)(l - 1) * H);
        const float* btm = (l == 0) ? bt1 : (btc + (size_t)(l - 1) * H);
        const ushort* WT = WTb + (size_t)l * H * H;

        if (l == 0)
            k_gemm<1><<<(n + 63) / 64, 256, 0, stream>>>(x, H, WT, hwb, n);
        else
            k_gemm<0><<<(n + 63) / 64, 256, 0, stream>>>(
                hcatb + (size_t)(l - 1) * H, LH, WT, hwb, n);

        hipMemsetAsync(stats, 0, 1024, stream);
        k_agg<<<(n + 31) / 32, 256, 0, stream>>>(hwb, rp, col, dinv, stats, aggb, n);
        k_bnapply<<<((size_t)n * H + 255) / 256, 256, 0, stream>>>(
            aggb, stats, gm, btm, hcatb + (size_t)l * H, n, LH);
    }

    // ---- pooling ----
    hipMemsetAsync(gcnt, 0, (size_t)GG * 4, stream);
    k_gcount<<<(n + 255) / 256, 256, 0, stream>>>(bat, gcnt, n);
    k_gscan<<<1, 64, 0, stream>>>(gcnt, gptr);
    k_pool<<<GG, LH, 0, stream>>>(hcatb, gptr, pooled);

    // ---- MLP head ----
    k_mlp1<<<GG, H, 0, stream>>>(pooled, Wl1, bl1, z);
    k_zstats<<<1, H, 0, stream>>>(z, zst);
    k_mlp2<<<GG, H, 0, stream>>>(z, zst, gl, btl, Wl2, bl2, out);
}

// Round 4
// 966.254 us; speedup vs baseline: 1.1873x; 1.1873x over previous
//
#include <hip/hip_runtime.h>
#include <math.h>

#define NN 100000
#define NE 1600000
#define H 128
#define LH 384
#define GG 512
#define CC 10
#define EPSBN 1e-5f
#define BSH 9  // bucket shift: 512 nodes per bucket

typedef __attribute__((ext_vector_type(4))) float f32x4;
typedef __attribute__((ext_vector_type(8))) short s16x8;
typedef unsigned long long u64;

__device__ inline ushort f2b(float f) {
    uint u = __float_as_uint(f);
    uint r = (u + 0x7FFFu + ((u >> 16) & 1u)) >> 16;
    return (ushort)r;
}
__device__ inline float b2f(ushort b) { return __uint_as_float(((uint)b) << 16); }
__device__ inline float blo(uint v) { return __uint_as_float(v << 16); }
__device__ inline float bhi(uint v) { return __uint_as_float(v & 0xFFFF0000u); }

// ---------------- W transpose + bf16 convert: WT[j*128+k] = W[k*128+j] ------

__global__ void k_wt(const float* __restrict__ W, ushort* __restrict__ WT, int nmat) {
    int mat = blockIdx.x >> 7;
    int k = blockIdx.x & 127;
    int j = threadIdx.x;  // 128 threads
    WT[(size_t)mat * H * H + j * H + k] = f2b(W[(size_t)mat * H * H + k * H + j]);
}

// ---------------- bucketed CSR build ----------------
// bucket b = dst >> BSH (512 nodes/bucket, nbuck <= 256)

__global__ void k_bhist(const int* __restrict__ dst, int* __restrict__ bhist,
                        int e, int nbuck) {
    __shared__ int lh[256];
    if (threadIdx.x < 256) lh[threadIdx.x] = 0;
    __syncthreads();
    int stride = gridDim.x * 256;
    for (int i = blockIdx.x * 256 + threadIdx.x; i < e; i += stride)
        atomicAdd(&lh[dst[i] >> BSH], 1);
    __syncthreads();
    int v = lh[threadIdx.x];
    if (threadIdx.x < nbuck && v) atomicAdd(&bhist[threadIdx.x], v);
}

__global__ void k_bscan(const int* __restrict__ bhist, int* __restrict__ bbase,
                        int* __restrict__ bcursor, int nbuck) {
    __shared__ int sh[256];
    int t = threadIdx.x;
    int v = (t < nbuck) ? bhist[t] : 0;
    sh[t] = v;
    __syncthreads();
    for (int off = 1; off < 256; off <<= 1) {
        int x = (t >= off) ? sh[t - off] : 0;
        __syncthreads();
        sh[t] += x;
        __syncthreads();
    }
    int run = sh[t] - v;
    if (t < nbuck) { bbase[t] = run; bcursor[t] = run; }
    if (t == nbuck) bbase[t] = run;  // == total e
    if (t == 255 && nbuck > 255) bbase[nbuck] = sh[255];
}

// block-aggregated scatter: LDS histogram -> 1 global atomic per (block,bucket)
__global__ void k_bin(const int* __restrict__ src, const int* __restrict__ dst,
                      int* __restrict__ bcursor, u64* __restrict__ ebuf, int e) {
    __shared__ int lh[256], gb[256], lcur[256];
    int t = threadIdx.x;
    int base = blockIdx.x * 4096;
    int lim = e - base; if (lim > 4096) lim = 4096;
    lh[t] = 0;
    __syncthreads();
    for (int i = t; i < lim; i += 256)
        atomicAdd(&lh[dst[base + i] >> BSH], 1);
    __syncthreads();
    int c = lh[t];
    if (c) gb[t] = atomicAdd(&bcursor[t], c);
    lcur[t] = 0;
    __syncthreads();
    for (int i = t; i < lim; i += 256) {
        int s = src[base + i], d = dst[base + i];
        int b = d >> BSH;
        int p = atomicAdd(&lcur[b], 1);
        ebuf[(size_t)gb[b] + p] = ((u64)(uint)d << 32) | (uint)s;
    }
}

__global__ void k_bfinal(const u64* __restrict__ ebuf, const int* __restrict__ bbase,
                         int* __restrict__ rp, float* __restrict__ dinv,
                         int* __restrict__ col, int n, int e) {
    __shared__ int hcnt[512], hoff[512], hcur[512];
    int b = blockIdx.x, t = threadIdx.x;
    int node0 = b << BSH;
    int e0 = bbase[b], e1 = bbase[b + 1];
    int m = e1 - e0;
    for (int j = t; j < 512; j += 256) hcnt[j] = 0;
    __syncthreads();
    for (int i = t; i < m; i += 256)
        atomicAdd(&hcnt[(int)(ebuf[e0 + i] >> 32) - node0], 1);
    __syncthreads();
    if (t == 0) {
        int run = 0;
        for (int j = 0; j < 512; ++j) { hoff[j] = run; run += hcnt[j]; }
    }
    __syncthreads();
    for (int j = t; j < 512; j += 256) {
        int node = node0 + j;
        if (node < n) {
            rp[node] = e0 + hoff[j];
            dinv[node] = rsqrtf((float)(hcnt[j] + 1));
        }
        hcur[j] = hoff[j];
    }
    if (b == 0 && t == 0) rp[n] = e;
    __syncthreads();
    for (int i = t; i < m; i += 256) {
        u64 u = ebuf[e0 + i];
        int d = (int)(u >> 32) - node0;
        int p = atomicAdd(&hcur[d], 1);
        col[e0 + p] = (int)(uint)u;
    }
}

// ---------------- MFMA GEMM: C[n,128]bf16 = A[n,lda] @ W[128,128] ----------

template <int AFP32>
__global__ __launch_bounds__(256) void k_gemm(
    const void* __restrict__ Ap, int lda, const ushort* __restrict__ WT,
    ushort* __restrict__ Cout, int n) {
    __shared__ ushort As[64][136];
    __shared__ ushort Ws[128][136];
    int t = threadIdx.x;
    int wave = t >> 6, lane = t & 63;
    int rowBase = blockIdx.x * 64;

    if (AFP32) {
        const float* A = (const float*)Ap;
        for (int i = t; i < 64 * 32; i += 256) {
            int r = i >> 5, c4 = i & 31;
            int row = rowBase + r;
            float4 v = make_float4(0.f, 0.f, 0.f, 0.f);
            if (row < n) v = *(const float4*)(A + (size_t)row * lda + c4 * 4);
            ushort4 o;
            o.x = f2b(v.x); o.y = f2b(v.y); o.z = f2b(v.z); o.w = f2b(v.w);
            *(ushort4*)(&As[r][c4 * 4]) = o;
        }
    } else {
        const ushort* A = (const ushort*)Ap;
        for (int i = t; i < 64 * 16; i += 256) {
            int r = i >> 4, c8 = i & 15;
            int row = rowBase + r;
            uint4 v = make_uint4(0u, 0u, 0u, 0u);
            if (row < n) v = *(const uint4*)(A + (size_t)row * lda + c8 * 8);
            *(uint4*)(&As[r][c8 * 8]) = v;
        }
    }
    for (int i = t; i < 128 * 16; i += 256) {
        int j = i >> 4, c8 = i & 15;
        uint4 v = *(const uint4*)(WT + j * H + c8 * 8);
        *(uint4*)(&Ws[j][c8 * 8]) = v;
    }
    __syncthreads();

    int m = lane & 15, q = lane >> 4;
    f32x4 acc[8];
#pragma unroll
    for (int c = 0; c < 8; ++c) acc[c] = (f32x4){0.f, 0.f, 0.f, 0.f};
#pragma unroll
    for (int kc = 0; kc < 4; ++kc) {
        int kof = kc * 32 + q * 8;
        s16x8 afrag = *(const s16x8*)(&As[wave * 16 + m][kof]);
#pragma unroll
        for (int c = 0; c < 8; ++c) {
            s16x8 bfrag = *(const s16x8*)(&Ws[c * 16 + m][kof]);
            acc[c] = __builtin_amdgcn_mfma_f32_16x16x32_bf16(afrag, bfrag, acc[c], 0, 0, 0);
        }
    }
#pragma unroll
    for (int c = 0; c < 8; ++c) {
        int colI = c * 16 + m;
#pragma unroll
        for (int r = 0; r < 4; ++r) {
            int row = rowBase + wave * 16 + q * 4 + r;
            if (row < n) Cout[(size_t)row * H + colI] = f2b(acc[c][r]);
        }
    }
}

// ---------------- Aggregation + fused BN stats ----------------

__global__ void k_agg(const ushort* __restrict__ hwb, const int* __restrict__ rp,
                      const int* __restrict__ col, const float* __restrict__ dinv,
                      float* __restrict__ stats, ushort* __restrict__ aggb, int n) {
    __shared__ float red[4][128];
    int wave = threadIdx.x >> 6, lane = threadIdx.x & 63;
    int nodeBase = blockIdx.x * 32 + wave * 8;
    const uint* hw32 = (const uint*)hwb;
    uint* agg32 = (uint*)aggb;
    float s0 = 0.f, s1 = 0.f, q0 = 0.f, q1 = 0.f;
    for (int ni = 0; ni < 8; ++ni) {
        int node = nodeBase + ni;
        if (node >= n) break;
        float dn = dinv[node];
        uint sv = hw32[(size_t)node * 64 + lane];
        float a0 = dn * blo(sv), a1 = dn * bhi(sv);
        int p = rp[node], pe = rp[node + 1];
        for (; p + 2 <= pe; p += 2) {
            int sA = col[p], sB = col[p + 1];
            float dA = dinv[sA], dB = dinv[sB];
            uint vA = hw32[(size_t)sA * 64 + lane];
            uint vB = hw32[(size_t)sB * 64 + lane];
            a0 += dA * blo(vA) + dB * blo(vB);
            a1 += dA * bhi(vA) + dB * bhi(vB);
        }
        if (p < pe) {
            int sA = col[p];
            float dA = dinv[sA];
            uint vA = hw32[(size_t)sA * 64 + lane];
            a0 += dA * blo(vA);
            a1 += dA * bhi(vA);
        }
        float o0 = dn * a0, o1 = dn * a1;
        s0 += o0; q0 += o0 * o0;
        s1 += o1; q1 += o1 * o1;
        agg32[(size_t)node * 64 + lane] = (uint)f2b(o0) | ((uint)f2b(o1) << 16);
    }
    red[wave][lane * 2] = s0;
    red[wave][lane * 2 + 1] = s1;
    __syncthreads();
    if (threadIdx.x < 128) {
        int f = threadIdx.x;
        atomicAdd(&stats[f], red[0][f] + red[1][f] + red[2][f] + red[3][f]);
    }
    __syncthreads();
    red[wave][lane * 2] = q0;
    red[wave][lane * 2 + 1] = q1;
    __syncthreads();
    if (threadIdx.x < 128) {
        int f = threadIdx.x;
        atomicAdd(&stats[128 + f], red[0][f] + red[1][f] + red[2][f] + red[3][f]);
    }
}

// ---------------- BN apply + ReLU -> bf16 concat buffer ----------------

__global__ void k_bnapply(const ushort* __restrict__ aggb, const float* __restrict__ stats,
                          const float* __restrict__ g, const float* __restrict__ bt,
                          ushort* __restrict__ outp, int n, int ldo) {
    int i = blockIdx.x * blockDim.x + threadIdx.x;
    if (i >= n * H) return;
    int f = i & 127;
    int r = i >> 7;
    float inv_n = 1.0f / (float)n;
    float mu = stats[f] * inv_n;
    float var = stats[128 + f] * inv_n - mu * mu;
    float v = (b2f(aggb[i]) - mu) * rsqrtf(var + EPSBN) * g[f] + bt[f];
    outp[(size_t)r * ldo + f] = f2b(fmaxf(v, 0.f));
}

// ---------------- Pooling ----------------

__global__ void k_gcount(const int* __restrict__ batch, int* __restrict__ gcnt, int n) {
    int i = blockIdx.x * blockDim.x + threadIdx.x;
    if (i < n) atomicAdd(&gcnt[batch[i]], 1);
}

__global__ void k_gscan(const int* __restrict__ gcnt, int* __restrict__ gptr) {
    if (threadIdx.x == 0 && blockIdx.x == 0) {
        int s = 0;
        for (int g = 0; g < GG; ++g) { gptr[g] = s; s += gcnt[g]; }
        gptr[GG] = s;
    }
}

__global__ void k_pool(const ushort* __restrict__ hcat, const int* __restrict__ gptr,
                       float* __restrict__ pooled) {
    int g = blockIdx.x;
    int f = threadIdx.x;  // 384 threads
    int r0 = gptr[g], r1 = gptr[g + 1];
    float s = 0.f;
    for (int r = r0; r < r1; ++r) s += b2f(hcat[(size_t)r * LH + f]);
    float c = (float)(r1 - r0);
    pooled[g * LH + f] = s / fmaxf(c, 1.f);
}

// ---------------- MLP head ----------------

__global__ void k_mlp1(const float* __restrict__ pooled, const float* __restrict__ Wl1,
                       const float* __restrict__ bl1, float* __restrict__ z) {
    __shared__ float row[LH];
    int g = blockIdx.x;
    int j = threadIdx.x;  // 128 threads
    for (int k = j; k < LH; k += H) row[k] = pooled[g * LH + k];
    __syncthreads();
    float acc = bl1[j];
    for (int k = 0; k < LH; ++k) acc += row[k] * Wl1[k * H + j];
    z[g * H + j] = acc;
}

__global__ void k_zstats(const float* __restrict__ z, float* __restrict__ st) {
    int j = threadIdx.x;  // 128 threads, 1 block
    float s = 0.f, q = 0.f;
    for (int g = 0; g < GG; ++g) {
        float v = z[g * H + j];
        s += v;
        q += v * v;
    }
    st[j] = s;
    st[128 + j] = q;
}

__global__ void k_mlp2(const float* __restrict__ z, const float* __restrict__ st,
                       const float* __restrict__ gl, const float* __restrict__ btl,
                       const float* __restrict__ Wl2, const float* __restrict__ bl2,
                       float* __restrict__ out) {
    __shared__ float zn[H];
    __shared__ float logit[CC];
    int g = blockIdx.x;
    int t = threadIdx.x;  // 128 threads
    float mu = st[t] * (1.f / GG);
    float var = st[128 + t] * (1.f / GG) - mu * mu;
    float v = (z[g * H + t] - mu) * rsqrtf(var + EPSBN) * gl[t] + btl[t];
    zn[t] = fmaxf(v, 0.f);
    __syncthreads();
    if (t < CC) {
        float acc = bl2[t];
        for (int k = 0; k < H; ++k) acc += zn[k] * Wl2[k * CC + t];
        logit[t] = acc;
    }
    __syncthreads();
    if (t == 0) {
        float m = -1e30f;
        for (int c = 0; c < CC; ++c) m = fmaxf(m, logit[c]);
        float se = 0.f;
        for (int c = 0; c < CC; ++c) se += expf(logit[c] - m);
        float lse = m + logf(se);
        for (int c = 0; c < CC; ++c) out[g * CC + c] = logit[c] - lse;
    }
}

// ---------------- launch ----------------

extern "C" void kernel_launch(void* const* d_in, const int* in_sizes, int n_in,
                              void* d_out, int out_size, void* d_ws, size_t ws_size,
                              hipStream_t stream) {
    const float* x   = (const float*)d_in[0];
    const int*   ei  = (const int*)d_in[1];
    const int*   bat = (const int*)d_in[2];
    const float* W1  = (const float*)d_in[3];
    const float* g1  = (const float*)d_in[5];
    const float* bt1 = (const float*)d_in[6];
    const float* Wc  = (const float*)d_in[7];
    const float* gc  = (const float*)d_in[9];
    const float* btc = (const float*)d_in[10];
    const float* Wl1 = (const float*)d_in[11];
    const float* bl1 = (const float*)d_in[12];
    const float* gl  = (const float*)d_in[13];
    const float* btl = (const float*)d_in[14];
    const float* Wl2 = (const float*)d_in[15];
    const float* bl2 = (const float*)d_in[16];
    float* out = (float*)d_out;

    const int n = in_sizes[2];
    const int e = in_sizes[1] / 2;
    const int* src = ei;
    const int* dst = ei + e;
    const int nbuck = (n + 511) / 512;  // <= 256

    size_t off = 0;
    char* base = (char*)d_ws;
    auto take = [&](size_t nbytes) -> void* {
        void* p = base + off;
        off += (nbytes + 255) & ~(size_t)255;
        return p;
    };
    int*    rp      = (int*)take((size_t)(NN + 1) * 4);
    int*    col     = (int*)take((size_t)NE * 4);
    float*  dinv    = (float*)take((size_t)NN * 4);
    int*    bhist   = (int*)take(1024 + 8);
    int*    bbase   = (int*)take(1024 + 8);
    int*    bcursor = (int*)take(1024 + 8);
    u64*    ebuf    = (u64*)take((size_t)NE * 8);
    float*  stats   = (float*)take(1024);
    int*    gcnt    = (int*)take((size_t)GG * 4);
    int*    gptr    = (int*)take((size_t)(GG + 1) * 4);
    ushort* WTb     = (ushort*)take((size_t)3 * H * H * 2);
    ushort* hwb     = (ushort*)take((size_t)NN * H * 2);
    ushort* aggb    = (ushort*)take((size_t)NN * H * 2);
    ushort* hcatb   = (ushort*)take((size_t)NN * LH * 2);
    float*  pooled  = (float*)take((size_t)GG * LH * 4);
    float*  z       = (float*)take((size_t)GG * H * 4);
    float*  zst     = (float*)take(1024);

    // ---- weight transpose/convert ----
    k_wt<<<H, H, 0, stream>>>(W1, WTb, 1);
    k_wt<<<2 * H, H, 0, stream>>>(Wc, WTb + (size_t)H * H, 2);

    // ---- bucketed CSR build ----
    hipMemsetAsync(bhist, 0, 1024 + 8, stream);
    k_bhist<<<256, 256, 0, stream>>>(dst, bhist, e, nbuck);
    k_bscan<<<1, 256, 0, stream>>>(bhist, bbase, bcursor, nbuck);
    k_bin<<<(e + 4095) / 4096, 256, 0, stream>>>(src, dst, bcursor, ebuf, e);
    k_bfinal<<<nbuck, 256, 0, stream>>>(ebuf, bbase, rp, dinv, col, n, e);

    // ---- 3 GCN layers ----
    for (int l = 0; l < 3; ++l) {
        const float* gm  = (l == 0) ? g1 : (gc + (size_t)(l - 1) * H);
        const float* btm = (l == 0) ? bt1 : (btc + (size_t)(l - 1) * H);
        const ushort* WT = WTb + (size_t)l * H * H;

        if (l == 0)
            k_gemm<1><<<(n + 63) / 64, 256, 0, stream>>>(x, H, WT, hwb, n);
        else
            k_gemm<0><<<(n + 63) / 64, 256, 0, stream>>>(
                hcatb + (size_t)(l - 1) * H, LH, WT, hwb, n);

        hipMemsetAsync(stats, 0, 1024, stream);
        k_agg<<<(n + 31) / 32, 256, 0, stream>>>(hwb, rp, col, dinv, stats, aggb, n);
        k_bnapply<<<((size_t)n * H + 255) / 256, 256, 0, stream>>>(
            aggb, stats, gm, btm, hcatb + (size_t)l * H, n, LH);
    }

    // ---- pooling ----
    hipMemsetAsync(gcnt, 0, (size_t)GG * 4, stream);
    k_gcount<<<(n + 255) / 256, 256, 0, stream>>>(bat, gcnt, n);
    k_gscan<<<1, 64, 0, stream>>>(gcnt, gptr);
    k_pool<<<GG, LH, 0, stream>>>(hcatb, gptr, pooled);

    // ---- MLP head ----
    k_mlp1<<<GG, H, 0, stream>>>(pooled, Wl1, bl1, z);
    k_zstats<<<1, H, 0, stream>>>(z, zst);
    k_mlp2<<<GG, H, 0, stream>>>(z, zst, gl, btl, Wl2, bl2, out);
}

// Round 5
// 810.452 us; speedup vs baseline: 1.4155x; 1.1922x over previous
//
#include <hip/hip_runtime.h>
#include <math.h>

#define NN 100000
#define NE 1600000
#define H 128
#define LH 384
#define GG 512
#define CC 10
#define EPSBN 1e-5f
#define BSH 9  // bucket shift: 512 nodes per bucket

typedef __attribute__((ext_vector_type(4))) float f32x4;
typedef __attribute__((ext_vector_type(8))) short s16x8;
typedef unsigned long long u64;

__device__ inline ushort f2b(float f) {
    uint u = __float_as_uint(f);
    uint r = (u + 0x7FFFu + ((u >> 16) & 1u)) >> 16;
    return (ushort)r;
}
__device__ inline float b2f(ushort b) { return __uint_as_float(((uint)b) << 16); }
__device__ inline float blo(uint v) { return __uint_as_float(v << 16); }
__device__ inline float bhi(uint v) { return __uint_as_float(v & 0xFFFF0000u); }

// ---------------- W transpose + bf16 convert: WT[j*128+k] = W[k*128+j] ------

__global__ void k_wt(const float* __restrict__ W, ushort* __restrict__ WT, int nmat) {
    int mat = blockIdx.x >> 7;
    int k = blockIdx.x & 127;
    int j = threadIdx.x;  // 128 threads
    WT[(size_t)mat * H * H + j * H + k] = f2b(W[(size_t)mat * H * H + k * H + j]);
}

// ---------------- bucketed CSR build ----------------

__global__ void k_bhist(const int* __restrict__ dst, int* __restrict__ bhist,
                        int e, int nbuck) {
    __shared__ int lh[256];
    lh[threadIdx.x] = 0;
    __syncthreads();
    int stride = gridDim.x * 256;
    for (int i = blockIdx.x * 256 + threadIdx.x; i < e; i += stride)
        atomicAdd(&lh[dst[i] >> BSH], 1);
    __syncthreads();
    int v = lh[threadIdx.x];
    if (threadIdx.x < nbuck && v) atomicAdd(&bhist[threadIdx.x], v);
}

__global__ void k_bscan(const int* __restrict__ bhist, int* __restrict__ bbase,
                        int* __restrict__ bcursor, int nbuck) {
    __shared__ int sh[256];
    int t = threadIdx.x;
    int v = (t < nbuck) ? bhist[t] : 0;
    sh[t] = v;
    __syncthreads();
    for (int off = 1; off < 256; off <<= 1) {
        int x = (t >= off) ? sh[t - off] : 0;
        __syncthreads();
        sh[t] += x;
        __syncthreads();
    }
    int run = sh[t] - v;
    if (t < nbuck) { bbase[t] = run; bcursor[t] = run; }
    if (t == nbuck) bbase[t] = run;
    if (t == 255 && nbuck > 255) bbase[nbuck] = sh[255];
}

// block-aggregated scatter: LDS histogram -> 1 global atomic per (block,bucket)
// packed u32 record: (dst & 511) << 17 | src
__global__ void k_bin(const int* __restrict__ src, const int* __restrict__ dst,
                      int* __restrict__ bcursor, uint* __restrict__ ebuf, int e) {
    __shared__ int lh[256], gb[256], lcur[256];
    int t = threadIdx.x;
    int base = blockIdx.x * 4096;
    int lim = e - base; if (lim > 4096) lim = 4096;
    lh[t] = 0;
    __syncthreads();
    for (int i = t; i < lim; i += 256)
        atomicAdd(&lh[dst[base + i] >> BSH], 1);
    __syncthreads();
    int c = lh[t];
    if (c) gb[t] = atomicAdd(&bcursor[t], c);
    lcur[t] = 0;
    __syncthreads();
    for (int i = t; i < lim; i += 256) {
        int s = src[base + i], d = dst[base + i];
        int b = d >> BSH;
        int p = atomicAdd(&lcur[b], 1);
        ebuf[(size_t)gb[b] + p] = ((uint)(d & 511) << 17) | (uint)s;
    }
}

__global__ void k_bfinal(const uint* __restrict__ ebuf, const int* __restrict__ bbase,
                         int* __restrict__ rp, float* __restrict__ dinv,
                         int* __restrict__ col, int n, int e) {
    __shared__ int hcnt[512], hoff[512], hcur[512];
    int b = blockIdx.x, t = threadIdx.x;
    int node0 = b << BSH;
    int e0 = bbase[b], e1 = bbase[b + 1];
    int m = e1 - e0;
    for (int j = t; j < 512; j += 256) hcnt[j] = 0;
    __syncthreads();
    for (int i = t; i < m; i += 256)
        atomicAdd(&hcnt[ebuf[e0 + i] >> 17], 1);
    __syncthreads();
    if (t == 0) {
        int run = 0;
        for (int j = 0; j < 512; ++j) { hoff[j] = run; run += hcnt[j]; }
    }
    __syncthreads();
    for (int j = t; j < 512; j += 256) {
        int node = node0 + j;
        if (node < n) {
            rp[node] = e0 + hoff[j];
            dinv[node] = rsqrtf((float)(hcnt[j] + 1));
        }
        hcur[j] = hoff[j];
    }
    if (b == 0 && t == 0) rp[n] = e;
    __syncthreads();
    for (int i = t; i < m; i += 256) {
        uint u = ebuf[e0 + i];
        int p = atomicAdd(&hcur[u >> 17], 1);
        col[e0 + p] = (int)(u & 0x1FFFFu);
    }
}

// ---------------- MFMA GEMM: C[n,128]bf16 = BNReLU(A)[n,128] @ W ----------
// MODE 0: A fp32 raw (layer 0). MODE 1: A bf16 + fused BN+ReLU (layers 1,2).

template <int MODE>
__global__ __launch_bounds__(256) void k_gemm(
    const void* __restrict__ Ap, const ushort* __restrict__ WT,
    const float* __restrict__ stats, const float* __restrict__ g,
    const float* __restrict__ bt, float inv_n,
    ushort* __restrict__ Cout, int n) {
    __shared__ ushort As[64][136];
    __shared__ ushort Ws[128][136];
    __shared__ float bsc[128], bshf[128];
    int t = threadIdx.x;
    int wave = t >> 6, lane = t & 63;
    int rowBase = blockIdx.x * 64;

    if (MODE == 1) {
        if (t < 128) {
            float mu = stats[t] * inv_n;
            float var = stats[128 + t] * inv_n - mu * mu;
            float sc = g[t] * rsqrtf(var + EPSBN);
            bsc[t] = sc;
            bshf[t] = bt[t] - mu * sc;
        }
        __syncthreads();
    }

    if (MODE == 0) {
        const float* A = (const float*)Ap;
        for (int i = t; i < 64 * 32; i += 256) {
            int r = i >> 5, c4 = i & 31;
            int row = rowBase + r;
            float4 v = make_float4(0.f, 0.f, 0.f, 0.f);
            if (row < n) v = *(const float4*)(A + (size_t)row * H + c4 * 4);
            ushort4 o;
            o.x = f2b(v.x); o.y = f2b(v.y); o.z = f2b(v.z); o.w = f2b(v.w);
            *(ushort4*)(&As[r][c4 * 4]) = o;
        }
    } else {
        const ushort* A = (const ushort*)Ap;
        for (int i = t; i < 64 * 16; i += 256) {
            int r = i >> 4, c8 = i & 15;
            int row = rowBase + r;
            uint4 v = make_uint4(0u, 0u, 0u, 0u);
            if (row < n) v = *(const uint4*)(A + (size_t)row * H + c8 * 8);
            const uint* pv = (const uint*)&v;
            ushort o[8];
#pragma unroll
            for (int j = 0; j < 4; ++j) {
                int f0 = c8 * 8 + 2 * j;
                float v0 = fmaxf(fmaf(blo(pv[j]), bsc[f0], bshf[f0]), 0.f);
                float v1 = fmaxf(fmaf(bhi(pv[j]), bsc[f0 + 1], bshf[f0 + 1]), 0.f);
                o[2 * j] = f2b(v0);
                o[2 * j + 1] = f2b(v1);
            }
            *(uint4*)(&As[r][c8 * 8]) = *(const uint4*)o;
        }
    }
    for (int i = t; i < 128 * 16; i += 256) {
        int j = i >> 4, c8 = i & 15;
        uint4 v = *(const uint4*)(WT + j * H + c8 * 8);
        *(uint4*)(&Ws[j][c8 * 8]) = v;
    }
    __syncthreads();

    int m = lane & 15, q = lane >> 4;
    f32x4 acc[8];
#pragma unroll
    for (int c = 0; c < 8; ++c) acc[c] = (f32x4){0.f, 0.f, 0.f, 0.f};
#pragma unroll
    for (int kc = 0; kc < 4; ++kc) {
        int kof = kc * 32 + q * 8;
        s16x8 afrag = *(const s16x8*)(&As[wave * 16 + m][kof]);
#pragma unroll
        for (int c = 0; c < 8; ++c) {
            s16x8 bfrag = *(const s16x8*)(&Ws[c * 16 + m][kof]);
            acc[c] = __builtin_amdgcn_mfma_f32_16x16x32_bf16(afrag, bfrag, acc[c], 0, 0, 0);
        }
    }
#pragma unroll
    for (int c = 0; c < 8; ++c) {
        int colI = c * 16 + m;
#pragma unroll
        for (int r = 0; r < 4; ++r) {
            int row = rowBase + wave * 16 + q * 4 + r;
            if (row < n) Cout[(size_t)row * H + colI] = f2b(acc[c][r]);
        }
    }
}

// ---------------- Aggregation + fused BN stats ----------------
// 16 lanes x dwordx4 per row; 4 edges per vmem instruction; 2-deep unroll.

__global__ void k_agg(const ushort* __restrict__ hwb, const int* __restrict__ rp,
                      const int* __restrict__ col, const float* __restrict__ dinv,
                      float* __restrict__ stats, ushort* __restrict__ aggb, int n) {
    __shared__ float red[4][128];
    int wave = threadIdx.x >> 6, lane = threadIdx.x & 63;
    int sub = lane >> 4, sl = lane & 15;
    int nodeBase = blockIdx.x * 32 + wave * 8;
    const uint4* hw4 = (const uint4*)hwb;
    uint4* agg4 = (uint4*)aggb;
    float st_s[8], st_q[8];
#pragma unroll
    for (int j = 0; j < 8; ++j) { st_s[j] = 0.f; st_q[j] = 0.f; }

    for (int ni = 0; ni < 8; ++ni) {
        int node = nodeBase + ni;
        if (node >= n) break;
        float dn = dinv[node];
        float acc[8];
        if (sub == 0) {
            uint4 v = hw4[(size_t)node * 16 + sl];
            const uint* pv = (const uint*)&v;
#pragma unroll
            for (int j = 0; j < 4; ++j) {
                acc[2 * j] = dn * blo(pv[j]);
                acc[2 * j + 1] = dn * bhi(pv[j]);
            }
        } else {
#pragma unroll
            for (int j = 0; j < 8; ++j) acc[j] = 0.f;
        }
        int s0 = rp[node], s1 = rp[node + 1];
        for (int p = s0; p < s1; p += 8) {
            int pa = p + sub, pb = p + 4 + sub;
            int ia = pa < s1 ? pa : s1 - 1;
            int ib = pb < s1 ? pb : s1 - 1;
            int sA = col[ia], sB = col[ib];
            float wA = (pa < s1) ? dinv[sA] : 0.f;
            float wB = (pb < s1) ? dinv[sB] : 0.f;
            uint4 vA = hw4[(size_t)sA * 16 + sl];
            uint4 vB = hw4[(size_t)sB * 16 + sl];
            const uint* pA = (const uint*)&vA;
            const uint* pB = (const uint*)&vB;
#pragma unroll
            for (int j = 0; j < 4; ++j) {
                acc[2 * j]     += wA * blo(pA[j]) + wB * blo(pB[j]);
                acc[2 * j + 1] += wA * bhi(pA[j]) + wB * bhi(pB[j]);
            }
        }
#pragma unroll
        for (int j = 0; j < 8; ++j) {
            acc[j] += __shfl_xor(acc[j], 16);
            acc[j] += __shfl_xor(acc[j], 32);
            acc[j] *= dn;
        }
        if (sub == 0) {
            uint4 o;
            uint* po = (uint*)&o;
#pragma unroll
            for (int j = 0; j < 4; ++j)
                po[j] = (uint)f2b(acc[2 * j]) | ((uint)f2b(acc[2 * j + 1]) << 16);
            agg4[(size_t)node * 16 + sl] = o;
#pragma unroll
            for (int j = 0; j < 8; ++j) {
                st_s[j] += acc[j];
                st_q[j] += acc[j] * acc[j];
            }
        }
    }
    if (sub == 0)
#pragma unroll
        for (int j = 0; j < 8; ++j) red[wave][sl * 8 + j] = st_s[j];
    __syncthreads();
    if (threadIdx.x < 128) {
        int f = threadIdx.x;
        atomicAdd(&stats[f], red[0][f] + red[1][f] + red[2][f] + red[3][f]);
    }
    __syncthreads();
    if (sub == 0)
#pragma unroll
        for (int j = 0; j < 8; ++j) red[wave][sl * 8 + j] = st_q[j];
    __syncthreads();
    if (threadIdx.x < 128) {
        int f = threadIdx.x;
        atomicAdd(&stats[128 + f], red[0][f] + red[1][f] + red[2][f] + red[3][f]);
    }
}

// ---------------- Pooling (BN+ReLU applied inline) ----------------

__global__ void k_gcount(const int* __restrict__ batch, int* __restrict__ gcnt, int n) {
    int i = blockIdx.x * blockDim.x + threadIdx.x;
    if (i < n) atomicAdd(&gcnt[batch[i]], 1);
}

__global__ void k_gscan(const int* __restrict__ gcnt, int* __restrict__ gptr) {
    if (threadIdx.x == 0 && blockIdx.x == 0) {
        int s = 0;
        for (int g = 0; g < GG; ++g) { gptr[g] = s; s += gcnt[g]; }
        gptr[GG] = s;
    }
}

__global__ void k_pool(const ushort* __restrict__ aggall, const float* __restrict__ statsall,
                       const float* __restrict__ g1, const float* __restrict__ bt1,
                       const float* __restrict__ gc, const float* __restrict__ btc,
                       const int* __restrict__ gptr, float* __restrict__ pooled,
                       float inv_n) {
    int g = blockIdx.x;
    int f = threadIdx.x;  // 384 threads
    int sec = f >> 7, feat = f & 127;
    const float* st = statsall + sec * 256;
    float mu = st[feat] * inv_n;
    float var = st[128 + feat] * inv_n - mu * mu;
    float gm = (sec == 0) ? g1[feat] : gc[(sec - 1) * H + feat];
    float bm = (sec == 0) ? bt1[feat] : btc[(sec - 1) * H + feat];
    float sc = gm * rsqrtf(var + EPSBN);
    float sh = bm - mu * sc;
    const ushort* a = aggall + (size_t)sec * NN * H;
    int r0 = gptr[g], r1 = gptr[g + 1];
    float s = 0.f;
    for (int r = r0; r < r1; ++r)
        s += fmaxf(fmaf(b2f(a[(size_t)r * H + feat]), sc, sh), 0.f);
    float c = (float)(r1 - r0);
    pooled[g * LH + f] = s / fmaxf(c, 1.f);
}

// ---------------- MLP head ----------------

__global__ void k_mlp1(const float* __restrict__ pooled, const float* __restrict__ Wl1,
                       const float* __restrict__ bl1, float* __restrict__ z) {
    __shared__ float row[LH];
    int g = blockIdx.x;
    int j = threadIdx.x;  // 128 threads
    for (int k = j; k < LH; k += H) row[k] = pooled[g * LH + k];
    __syncthreads();
    float acc = bl1[j];
    for (int k = 0; k < LH; ++k) acc += row[k] * Wl1[k * H + j];
    z[g * H + j] = acc;
}

__global__ void k_zstats(const float* __restrict__ z, float* __restrict__ st) {
    int j = threadIdx.x;  // 128 threads, 1 block
    float s = 0.f, q = 0.f;
    for (int g = 0; g < GG; ++g) {
        float v = z[g * H + j];
        s += v;
        q += v * v;
    }
    st[j] = s;
    st[128 + j] = q;
}

__global__ void k_mlp2(const float* __restrict__ z, const float* __restrict__ st,
                       const float* __restrict__ gl, const float* __restrict__ btl,
                       const float* __restrict__ Wl2, const float* __restrict__ bl2,
                       float* __restrict__ out) {
    __shared__ float zn[H];
    __shared__ float logit[CC];
    int g = blockIdx.x;
    int t = threadIdx.x;  // 128 threads
    float mu = st[t] * (1.f / GG);
    float var = st[128 + t] * (1.f / GG) - mu * mu;
    float v = (z[g * H + t] - mu) * rsqrtf(var + EPSBN) * gl[t] + btl[t];
    zn[t] = fmaxf(v, 0.f);
    __syncthreads();
    if (t < CC) {
        float acc = bl2[t];
        for (int k = 0; k < H; ++k) acc += zn[k] * Wl2[k * CC + t];
        logit[t] = acc;
    }
    __syncthreads();
    if (t == 0) {
        float m = -1e30f;
        for (int c = 0; c < CC; ++c) m = fmaxf(m, logit[c]);
        float se = 0.f;
        for (int c = 0; c < CC; ++c) se += expf(logit[c] - m);
        float lse = m + logf(se);
        for (int c = 0; c < CC; ++c) out[g * CC + c] = logit[c] - lse;
    }
}

// ---------------- launch ----------------

extern "C" void kernel_launch(void* const* d_in, const int* in_sizes, int n_in,
                              void* d_out, int out_size, void* d_ws, size_t ws_size,
                              hipStream_t stream) {
    const float* x   = (const float*)d_in[0];
    const int*   ei  = (const int*)d_in[1];
    const int*   bat = (const int*)d_in[2];
    const float* W1  = (const float*)d_in[3];
    const float* g1  = (const float*)d_in[5];
    const float* bt1 = (const float*)d_in[6];
    const float* Wc  = (const float*)d_in[7];
    const float* gc  = (const float*)d_in[9];
    const float* btc = (const float*)d_in[10];
    const float* Wl1 = (const float*)d_in[11];
    const float* bl1 = (const float*)d_in[12];
    const float* gl  = (const float*)d_in[13];
    const float* btl = (const float*)d_in[14];
    const float* Wl2 = (const float*)d_in[15];
    const float* bl2 = (const float*)d_in[16];
    float* out = (float*)d_out;

    const int n = in_sizes[2];
    const int e = in_sizes[1] / 2;
    const int* src = ei;
    const int* dst = ei + e;
    const int nbuck = (n + 511) / 512;  // <= 256
    const float inv_n = 1.0f / (float)n;

    size_t off = 0;
    char* base = (char*)d_ws;
    auto take = [&](size_t nbytes) -> void* {
        void* p = base + off;
        off += (nbytes + 255) & ~(size_t)255;
        return p;
    };
    int*    rp      = (int*)take((size_t)(NN + 1) * 4);
    int*    col     = (int*)take((size_t)NE * 4);
    float*  dinv    = (float*)take((size_t)NN * 4);
    int*    bhist   = (int*)take(1024 + 8);
    int*    bbase   = (int*)take(1024 + 8);
    int*    bcursor = (int*)take(1024 + 8);
    uint*   ebuf    = (uint*)take((size_t)NE * 4);
    float*  stats   = (float*)take(3 * 1024);
    int*    gcnt    = (int*)take((size_t)GG * 4);
    int*    gptr    = (int*)take((size_t)(GG + 1) * 4);
    ushort* WTb     = (ushort*)take((size_t)3 * H * H * 2);
    ushort* hwb     = (ushort*)take((size_t)NN * H * 2);
    ushort* aggb    = (ushort*)take((size_t)3 * NN * H * 2);
    float*  pooled  = (float*)take((size_t)GG * LH * 4);
    float*  z       = (float*)take((size_t)GG * H * 4);
    float*  zst     = (float*)take(1024);

    // ---- weight transpose/convert ----
    k_wt<<<H, H, 0, stream>>>(W1, WTb, 1);
    k_wt<<<2 * H, H, 0, stream>>>(Wc, WTb + (size_t)H * H, 2);

    // ---- bucketed CSR build ----
    hipMemsetAsync(bhist, 0, 1024 + 8, stream);
    k_bhist<<<256, 256, 0, stream>>>(dst, bhist, e, nbuck);
    k_bscan<<<1, 256, 0, stream>>>(bhist, bbase, bcursor, nbuck);
    k_bin<<<(e + 4095) / 4096, 256, 0, stream>>>(src, dst, bcursor, ebuf, e);
    k_bfinal<<<nbuck, 256, 0, stream>>>(ebuf, bbase, rp, dinv, col, n, e);

    // ---- 3 GCN layers (BN+ReLU of layer l-1 fused into layer l's GEMM) ----
    hipMemsetAsync(stats, 0, 3 * 1024, stream);
    for (int l = 0; l < 3; ++l) {
        const ushort* WT = WTb + (size_t)l * H * H;

        if (l == 0) {
            k_gemm<0><<<(n + 63) / 64, 256, 0, stream>>>(
                x, WT, nullptr, nullptr, nullptr, inv_n, hwb, n);
        } else {
            // input to layer l is BN_{l-1}(agg[l-1]): params g1/bt1 for l==1,
            // gc[0]/btc[0] for l==2
            const float* gm  = (l == 1) ? g1 : gc;
            const float* btm = (l == 1) ? bt1 : btc;
            k_gemm<1><<<(n + 63) / 64, 256, 0, stream>>>(
                aggb + (size_t)(l - 1) * NN * H, WT, stats + (size_t)(l - 1) * 256,
                gm, btm, inv_n, hwb, n);
        }
        k_agg<<<(n + 31) / 32, 256, 0, stream>>>(
            hwb, rp, col, dinv, stats + (size_t)l * 256, aggb + (size_t)l * NN * H, n);
    }

    // ---- pooling ----
    hipMemsetAsync(gcnt, 0, (size_t)GG * 4, stream);
    k_gcount<<<(n + 255) / 256, 256, 0, stream>>>(bat, gcnt, n);
    k_gscan<<<1, 64, 0, stream>>>(gcnt, gptr);
    k_pool<<<GG, LH, 0, stream>>>(aggb, stats, g1, bt1, gc, btc, gptr, pooled, inv_n);

    // ---- MLP head ----
    k_mlp1<<<GG, H, 0, stream>>>(pooled, Wl1, bl1, z);
    k_zstats<<<1, H, 0, stream>>>(z, zst);
    k_mlp2<<<GG, H, 0, stream>>>(z, zst, gl, btl, Wl2, bl2, out);
}

// Round 6
// 744.705 us; speedup vs baseline: 1.5405x; 1.0883x over previous
//
#include <hip/hip_runtime.h>
#include <math.h>

#define NN 100000
#define NE 1600000
#define H 128
#define LH 384
#define GG 512
#define CC 10
#define EPSBN 1e-5f
#define BSH 9  // bucket shift: 512 nodes per bucket

typedef __attribute__((ext_vector_type(4))) float f32x4;
typedef __attribute__((ext_vector_type(8))) short s16x8;
typedef unsigned long long u64;

__device__ inline ushort f2b(float f) {
    uint u = __float_as_uint(f);
    uint r = (u + 0x7FFFu + ((u >> 16) & 1u)) >> 16;
    return (ushort)r;
}
__device__ inline float b2f(ushort b) { return __uint_as_float(((uint)b) << 16); }
__device__ inline float blo(uint v) { return __uint_as_float(v << 16); }
__device__ inline float bhi(uint v) { return __uint_as_float(v & 0xFFFF0000u); }

// ---------------- W transpose + bf16 convert: WT[j*128+k] = W[k*128+j] ------

__global__ void k_wt(const float* __restrict__ W, ushort* __restrict__ WT, int nmat) {
    int mat = blockIdx.x >> 7;
    int k = blockIdx.x & 127;
    int j = threadIdx.x;  // 128 threads
    WT[(size_t)mat * H * H + j * H + k] = f2b(W[(size_t)mat * H * H + k * H + j]);
}

// ---------------- bucketed CSR build ----------------

__global__ void k_bhist(const int* __restrict__ dst, int* __restrict__ bhist,
                        int e, int nbuck) {
    __shared__ int lh[256];
    lh[threadIdx.x] = 0;
    __syncthreads();
    int stride = gridDim.x * 256;
    for (int i = blockIdx.x * 256 + threadIdx.x; i < e; i += stride)
        atomicAdd(&lh[dst[i] >> BSH], 1);
    __syncthreads();
    int v = lh[threadIdx.x];
    if (threadIdx.x < nbuck && v) atomicAdd(&bhist[threadIdx.x], v);
}

__global__ void k_bscan(const int* __restrict__ bhist, int* __restrict__ bbase,
                        int* __restrict__ bcursor, int nbuck) {
    __shared__ int sh[256];
    int t = threadIdx.x;
    int v = (t < nbuck) ? bhist[t] : 0;
    sh[t] = v;
    __syncthreads();
    for (int off = 1; off < 256; off <<= 1) {
        int x = (t >= off) ? sh[t - off] : 0;
        __syncthreads();
        sh[t] += x;
        __syncthreads();
    }
    int run = sh[t] - v;
    if (t < nbuck) { bbase[t] = run; bcursor[t] = run; }
    if (t == nbuck) bbase[t] = run;
    if (t == 255 && nbuck > 255) bbase[nbuck] = sh[255];
}

// block-aggregated scatter: LDS histogram -> 1 global atomic per (block,bucket)
// packed u32 record: (dst & 511) << 17 | src
__global__ void k_bin(const int* __restrict__ src, const int* __restrict__ dst,
                      int* __restrict__ bcursor, uint* __restrict__ ebuf, int e) {
    __shared__ int lh[256], gb[256], lcur[256];
    int t = threadIdx.x;
    int base = blockIdx.x * 4096;
    int lim = e - base; if (lim > 4096) lim = 4096;
    lh[t] = 0;
    __syncthreads();
    for (int i = t; i < lim; i += 256)
        atomicAdd(&lh[dst[base + i] >> BSH], 1);
    __syncthreads();
    int c = lh[t];
    if (c) gb[t] = atomicAdd(&bcursor[t], c);
    lcur[t] = 0;
    __syncthreads();
    for (int i = t; i < lim; i += 256) {
        int s = src[base + i], d = dst[base + i];
        int b = d >> BSH;
        int p = atomicAdd(&lcur[b], 1);
        ebuf[(size_t)gb[b] + p] = ((uint)(d & 511) << 17) | (uint)s;
    }
}

__global__ void k_bfinal(const uint* __restrict__ ebuf, const int* __restrict__ bbase,
                         int* __restrict__ rp, float* __restrict__ dinv,
                         int* __restrict__ col, int n, int e) {
    __shared__ int hcnt[512], hoff[512], hcur[512];
    int b = blockIdx.x, t = threadIdx.x;
    int node0 = b << BSH;
    int e0 = bbase[b], e1 = bbase[b + 1];
    int m = e1 - e0;
    for (int j = t; j < 512; j += 256) hcnt[j] = 0;
    __syncthreads();
    for (int i = t; i < m; i += 256)
        atomicAdd(&hcnt[ebuf[e0 + i] >> 17], 1);
    __syncthreads();
    if (t == 0) {
        int run = 0;
        for (int j = 0; j < 512; ++j) { hoff[j] = run; run += hcnt[j]; }
    }
    __syncthreads();
    for (int j = t; j < 512; j += 256) {
        int node = node0 + j;
        if (node < n) {
            rp[node] = e0 + hoff[j];
            dinv[node] = rsqrtf((float)(hcnt[j] + 1));
        }
        hcur[j] = hoff[j];
    }
    if (b == 0 && t == 0) rp[n] = e;
    __syncthreads();
    for (int i = t; i < m; i += 256) {
        uint u = ebuf[e0 + i];
        int p = atomicAdd(&hcur[u >> 17], 1);
        col[e0 + p] = (int)(u & 0x1FFFFu);
    }
}

// ---------------- edge records: (dinv[src] bits << 32) | src ----------------

__global__ void k_erec(const int* __restrict__ col, const float* __restrict__ dinv,
                       u64* __restrict__ erec, int e) {
    int i = blockIdx.x * 256 + threadIdx.x;
    if (i < e) {
        int s = col[i];
        erec[i] = ((u64)__float_as_uint(dinv[s]) << 32) | (uint)s;
    }
}

// ---------------- MFMA GEMM: C[n,128]bf16 = BNReLU(A)[n,128] @ W ----------
// MODE 0: A fp32 raw (layer 0). MODE 1: A bf16 + fused BN+ReLU (layers 1,2).

template <int MODE>
__global__ __launch_bounds__(256) void k_gemm(
    const void* __restrict__ Ap, const ushort* __restrict__ WT,
    const float* __restrict__ stats, const float* __restrict__ g,
    const float* __restrict__ bt, float inv_n,
    ushort* __restrict__ Cout, int n) {
    __shared__ ushort As[64][136];
    __shared__ ushort Ws[128][136];
    __shared__ float bsc[128], bshf[128];
    int t = threadIdx.x;
    int wave = t >> 6, lane = t & 63;
    int rowBase = blockIdx.x * 64;

    if (MODE == 1) {
        if (t < 128) {
            float mu = stats[t] * inv_n;
            float var = stats[128 + t] * inv_n - mu * mu;
            float sc = g[t] * rsqrtf(var + EPSBN);
            bsc[t] = sc;
            bshf[t] = bt[t] - mu * sc;
        }
        __syncthreads();
    }

    if (MODE == 0) {
        const float* A = (const float*)Ap;
        for (int i = t; i < 64 * 32; i += 256) {
            int r = i >> 5, c4 = i & 31;
            int row = rowBase + r;
            float4 v = make_float4(0.f, 0.f, 0.f, 0.f);
            if (row < n) v = *(const float4*)(A + (size_t)row * H + c4 * 4);
            ushort4 o;
            o.x = f2b(v.x); o.y = f2b(v.y); o.z = f2b(v.z); o.w = f2b(v.w);
            *(ushort4*)(&As[r][c4 * 4]) = o;
        }
    } else {
        const ushort* A = (const ushort*)Ap;
        for (int i = t; i < 64 * 16; i += 256) {
            int r = i >> 4, c8 = i & 15;
            int row = rowBase + r;
            uint4 v = make_uint4(0u, 0u, 0u, 0u);
            if (row < n) v = *(const uint4*)(A + (size_t)row * H + c8 * 8);
            const uint* pv = (const uint*)&v;
            ushort o[8];
#pragma unroll
            for (int j = 0; j < 4; ++j) {
                int f0 = c8 * 8 + 2 * j;
                float v0 = fmaxf(fmaf(blo(pv[j]), bsc[f0], bshf[f0]), 0.f);
                float v1 = fmaxf(fmaf(bhi(pv[j]), bsc[f0 + 1], bshf[f0 + 1]), 0.f);
                o[2 * j] = f2b(v0);
                o[2 * j + 1] = f2b(v1);
            }
            *(uint4*)(&As[r][c8 * 8]) = *(const uint4*)o;
        }
    }
    for (int i = t; i < 128 * 16; i += 256) {
        int j = i >> 4, c8 = i & 15;
        uint4 v = *(const uint4*)(WT + j * H + c8 * 8);
        *(uint4*)(&Ws[j][c8 * 8]) = v;
    }
    __syncthreads();

    int m = lane & 15, q = lane >> 4;
    f32x4 acc[8];
#pragma unroll
    for (int c = 0; c < 8; ++c) acc[c] = (f32x4){0.f, 0.f, 0.f, 0.f};
#pragma unroll
    for (int kc = 0; kc < 4; ++kc) {
        int kof = kc * 32 + q * 8;
        s16x8 afrag = *(const s16x8*)(&As[wave * 16 + m][kof]);
#pragma unroll
        for (int c = 0; c < 8; ++c) {
            s16x8 bfrag = *(const s16x8*)(&Ws[c * 16 + m][kof]);
            acc[c] = __builtin_amdgcn_mfma_f32_16x16x32_bf16(afrag, bfrag, acc[c], 0, 0, 0);
        }
    }
#pragma unroll
    for (int c = 0; c < 8; ++c) {
        int colI = c * 16 + m;
#pragma unroll
        for (int r = 0; r < 4; ++r) {
            int row = rowBase + wave * 16 + q * 4 + r;
            if (row < n) Cout[(size_t)row * H + colI] = f2b(acc[c][r]);
        }
    }
}

// ---------------- Aggregation + fused BN stats ----------------
// 16 lanes x dwordx4 per row; 4-deep edge unroll per subgroup:
// 16 rows in flight per wave. Edge records carry (dinv[src], src).

__global__ __launch_bounds__(256) void k_agg(
    const ushort* __restrict__ hwb, const int* __restrict__ rp,
    const u64* __restrict__ erec, const float* __restrict__ dinv,
    float* __restrict__ stats, ushort* __restrict__ aggb, int n) {
    __shared__ float red[4][128];
    int wave = threadIdx.x >> 6, lane = threadIdx.x & 63;
    int sub = lane >> 4, sl = lane & 15;
    int nodeBase = blockIdx.x * 32 + wave * 8;
    const uint4* hw4 = (const uint4*)hwb;
    uint4* agg4 = (uint4*)aggb;
    float st_s[8], st_q[8];
#pragma unroll
    for (int j = 0; j < 8; ++j) { st_s[j] = 0.f; st_q[j] = 0.f; }

    for (int ni = 0; ni < 8; ++ni) {
        int node = nodeBase + ni;
        if (node >= n) break;
        float dn = dinv[node];
        float acc[8];
        if (sub == 0) {
            uint4 v = hw4[(size_t)node * 16 + sl];
            const uint* pv = (const uint*)&v;
#pragma unroll
            for (int j = 0; j < 4; ++j) {
                acc[2 * j] = dn * blo(pv[j]);
                acc[2 * j + 1] = dn * bhi(pv[j]);
            }
        } else {
#pragma unroll
            for (int j = 0; j < 8; ++j) acc[j] = 0.f;
        }
        int s0 = rp[node], s1 = rp[node + 1];
        for (int p = s0; p < s1; p += 16) {
            int eb = p + sub * 4;
            int i0 = eb < s1 ? eb : s1 - 1;
            int i1 = eb + 1 < s1 ? eb + 1 : s1 - 1;
            int i2 = eb + 2 < s1 ? eb + 2 : s1 - 1;
            int i3 = eb + 3 < s1 ? eb + 3 : s1 - 1;
            u64 r0 = erec[i0], r1 = erec[i1], r2 = erec[i2], r3 = erec[i3];
            float w0 = (eb < s1) ? __uint_as_float((uint)(r0 >> 32)) : 0.f;
            float w1 = (eb + 1 < s1) ? __uint_as_float((uint)(r1 >> 32)) : 0.f;
            float w2 = (eb + 2 < s1) ? __uint_as_float((uint)(r2 >> 32)) : 0.f;
            float w3 = (eb + 3 < s1) ? __uint_as_float((uint)(r3 >> 32)) : 0.f;
            uint4 v0 = hw4[(size_t)(uint)r0 * 16 + sl];
            uint4 v1 = hw4[(size_t)(uint)r1 * 16 + sl];
            uint4 v2 = hw4[(size_t)(uint)r2 * 16 + sl];
            uint4 v3 = hw4[(size_t)(uint)r3 * 16 + sl];
            const uint* p0 = (const uint*)&v0;
            const uint* p1 = (const uint*)&v1;
            const uint* p2 = (const uint*)&v2;
            const uint* p3 = (const uint*)&v3;
#pragma unroll
            for (int j = 0; j < 4; ++j) {
                acc[2 * j]     += w0 * blo(p0[j]) + w1 * blo(p1[j])
                                + w2 * blo(p2[j]) + w3 * blo(p3[j]);
                acc[2 * j + 1] += w0 * bhi(p0[j]) + w1 * bhi(p1[j])
                                + w2 * bhi(p2[j]) + w3 * bhi(p3[j]);
            }
        }
#pragma unroll
        for (int j = 0; j < 8; ++j) {
            acc[j] += __shfl_xor(acc[j], 16);
            acc[j] += __shfl_xor(acc[j], 32);
            acc[j] *= dn;
        }
        if (sub == 0) {
            uint4 o;
            uint* po = (uint*)&o;
#pragma unroll
            for (int j = 0; j < 4; ++j)
                po[j] = (uint)f2b(acc[2 * j]) | ((uint)f2b(acc[2 * j + 1]) << 16);
            agg4[(size_t)node * 16 + sl] = o;
#pragma unroll
            for (int j = 0; j < 8; ++j) {
                st_s[j] += acc[j];
                st_q[j] += acc[j] * acc[j];
            }
        }
    }
    if (sub == 0)
#pragma unroll
        for (int j = 0; j < 8; ++j) red[wave][sl * 8 + j] = st_s[j];
    __syncthreads();
    if (threadIdx.x < 128) {
        int f = threadIdx.x;
        atomicAdd(&stats[f], red[0][f] + red[1][f] + red[2][f] + red[3][f]);
    }
    __syncthreads();
    if (sub == 0)
#pragma unroll
        for (int j = 0; j < 8; ++j) red[wave][sl * 8 + j] = st_q[j];
    __syncthreads();
    if (threadIdx.x < 128) {
        int f = threadIdx.x;
        atomicAdd(&stats[128 + f], red[0][f] + red[1][f] + red[2][f] + red[3][f]);
    }
}

// ---------------- Pooling (BN+ReLU applied inline) ----------------

__global__ void k_gbound(const int* __restrict__ batch, int* __restrict__ gptr, int n) {
    int g = blockIdx.x * 256 + threadIdx.x;
    if (g > GG) return;
    int lo = 0, hi = n;
    while (lo < hi) {
        int mid = (lo + hi) >> 1;
        if (batch[mid] < g) lo = mid + 1; else hi = mid;
    }
    gptr[g] = lo;
}

__global__ void k_pool(const ushort* __restrict__ aggall, const float* __restrict__ statsall,
                       const float* __restrict__ g1, const float* __restrict__ bt1,
                       const float* __restrict__ gc, const float* __restrict__ btc,
                       const int* __restrict__ gptr, float* __restrict__ pooled,
                       float inv_n) {
    int g = blockIdx.x;
    int f = threadIdx.x;  // 384 threads
    int sec = f >> 7, feat = f & 127;
    const float* st = statsall + sec * 256;
    float mu = st[feat] * inv_n;
    float var = st[128 + feat] * inv_n - mu * mu;
    float gm = (sec == 0) ? g1[feat] : gc[(sec - 1) * H + feat];
    float bm = (sec == 0) ? bt1[feat] : btc[(sec - 1) * H + feat];
    float sc = gm * rsqrtf(var + EPSBN);
    float sh = bm - mu * sc;
    const ushort* a = aggall + (size_t)sec * NN * H;
    int r0 = gptr[g], r1 = gptr[g + 1];
    float s = 0.f;
    for (int r = r0; r < r1; ++r)
        s += fmaxf(fmaf(b2f(a[(size_t)r * H + feat]), sc, sh), 0.f);
    float c = (float)(r1 - r0);
    pooled[g * LH + f] = s / fmaxf(c, 1.f);
}

// ---------------- MLP head ----------------

__global__ void k_mlp1(const float* __restrict__ pooled, const float* __restrict__ Wl1,
                       const float* __restrict__ bl1, float* __restrict__ z) {
    __shared__ float row[LH];
    int g = blockIdx.x;
    int j = threadIdx.x;  // 128 threads
    for (int k = j; k < LH; k += H) row[k] = pooled[g * LH + k];
    __syncthreads();
    float acc = bl1[j];
    for (int k = 0; k < LH; ++k) acc += row[k] * Wl1[k * H + j];
    z[g * H + j] = acc;
}

__global__ void k_zstats(const float* __restrict__ z, float* __restrict__ st) {
    int j = threadIdx.x;  // 128 threads, 1 block
    float s = 0.f, q = 0.f;
    for (int g = 0; g < GG; ++g) {
        float v = z[g * H + j];
        s += v;
        q += v * v;
    }
    st[j] = s;
    st[128 + j] = q;
}

__global__ void k_mlp2(const float* __restrict__ z, const float* __restrict__ st,
                       const float* __restrict__ gl, const float* __restrict__ btl,
                       const float* __restrict__ Wl2, const float* __restrict__ bl2,
                       float* __restrict__ out) {
    __shared__ float zn[H];
    __shared__ float logit[CC];
    int g = blockIdx.x;
    int t = threadIdx.x;  // 128 threads
    float mu = st[t] * (1.f / GG);
    float var = st[128 + t] * (1.f / GG) - mu * mu;
    float v = (z[g * H + t] - mu) * rsqrtf(var + EPSBN) * gl[t] + btl[t];
    zn[t] = fmaxf(v, 0.f);
    __syncthreads();
    if (t < CC) {
        float acc = bl2[t];
        for (int k = 0; k < H; ++k) acc += zn[k] * Wl2[k * CC + t];
        logit[t] = acc;
    }
    __syncthreads();
    if (t == 0) {
        float m = -1e30f;
        for (int c = 0; c < CC; ++c) m = fmaxf(m, logit[c]);
        float se = 0.f;
        for (int c = 0; c < CC; ++c) se += expf(logit[c] - m);
        float lse = m + logf(se);
        for (int c = 0; c < CC; ++c) out[g * CC + c] = logit[c] - lse;
    }
}

// ---------------- launch ----------------

extern "C" void kernel_launch(void* const* d_in, const int* in_sizes, int n_in,
                              void* d_out, int out_size, void* d_ws, size_t ws_size,
                              hipStream_t stream) {
    const float* x   = (const float*)d_in[0];
    const int*   ei  = (const int*)d_in[1];
    const int*   bat = (const int*)d_in[2];
    const float* W1  = (const float*)d_in[3];
    const float* g1  = (const float*)d_in[5];
    const float* bt1 = (const float*)d_in[6];
    const float* Wc  = (const float*)d_in[7];
    const float* gc  = (const float*)d_in[9];
    const float* btc = (const float*)d_in[10];
    const float* Wl1 = (const float*)d_in[11];
    const float* bl1 = (const float*)d_in[12];
    const float* gl  = (const float*)d_in[13];
    const float* btl = (const float*)d_in[14];
    const float* Wl2 = (const float*)d_in[15];
    const float* bl2 = (const float*)d_in[16];
    float* out = (float*)d_out;

    const int n = in_sizes[2];
    const int e = in_sizes[1] / 2;
    const int* src = ei;
    const int* dst = ei + e;
    const int nbuck = (n + 511) / 512;  // <= 256
    const float inv_n = 1.0f / (float)n;

    size_t off = 0;
    char* base = (char*)d_ws;
    auto take = [&](size_t nbytes) -> void* {
        void* p = base + off;
        off += (nbytes + 255) & ~(size_t)255;
        return p;
    };
    int*    rp      = (int*)take((size_t)(NN + 1) * 4);
    int*    col     = (int*)take((size_t)NE * 4);
    float*  dinv    = (float*)take((size_t)NN * 4);
    int*    bhist   = (int*)take(1024 + 8);
    int*    bbase   = (int*)take(1024 + 8);
    int*    bcursor = (int*)take(1024 + 8);
    uint*   ebuf    = (uint*)take((size_t)NE * 4);
    u64*    erec    = (u64*)take((size_t)NE * 8);
    float*  stats   = (float*)take(3 * 1024);
    int*    gptr    = (int*)take((size_t)(GG + 1) * 4);
    ushort* WTb     = (ushort*)take((size_t)3 * H * H * 2);
    ushort* hwb     = (ushort*)take((size_t)NN * H * 2);
    ushort* aggb    = (ushort*)take((size_t)3 * NN * H * 2);
    float*  pooled  = (float*)take((size_t)GG * LH * 4);
    float*  z       = (float*)take((size_t)GG * H * 4);
    float*  zst     = (float*)take(1024);

    // ---- weight transpose/convert ----
    k_wt<<<H, H, 0, stream>>>(W1, WTb, 1);
    k_wt<<<2 * H, H, 0, stream>>>(Wc, WTb + (size_t)H * H, 2);

    // ---- bucketed CSR build ----
    hipMemsetAsync(bhist, 0, 1024 + 8, stream);
    k_bhist<<<256, 256, 0, stream>>>(dst, bhist, e, nbuck);
    k_bscan<<<1, 256, 0, stream>>>(bhist, bbase, bcursor, nbuck);
    k_bin<<<(e + 4095) / 4096, 256, 0, stream>>>(src, dst, bcursor, ebuf, e);
    k_bfinal<<<nbuck, 256, 0, stream>>>(ebuf, bbase, rp, dinv, col, n, e);
    k_erec<<<(e + 255) / 256, 256, 0, stream>>>(col, dinv, erec, e);

    // ---- 3 GCN layers (BN+ReLU of layer l-1 fused into layer l's GEMM) ----
    hipMemsetAsync(stats, 0, 3 * 1024, stream);
    for (int l = 0; l < 3; ++l) {
        const ushort* WT = WTb + (size_t)l * H * H;

        if (l == 0) {
            k_gemm<0><<<(n + 63) / 64, 256, 0, stream>>>(
                x, WT, nullptr, nullptr, nullptr, inv_n, hwb, n);
        } else {
            const float* gm  = (l == 1) ? g1 : gc;
            const float* btm = (l == 1) ? bt1 : btc;
            k_gemm<1><<<(n + 63) / 64, 256, 0, stream>>>(
                aggb + (size_t)(l - 1) * NN * H, WT, stats + (size_t)(l - 1) * 256,
                gm, btm, inv_n, hwb, n);
        }
        k_agg<<<(n + 31) / 32, 256, 0, stream>>>(
            hwb, rp, erec, dinv, stats + (size_t)l * 256, aggb + (size_t)l * NN * H, n);
    }

    // ---- pooling ----
    k_gbound<<<3, 256, 0, stream>>>(bat, gptr, n);
    k_pool<<<GG, LH, 0, stream>>>(aggb, stats, g1, bt1, gc, btc, gptr, pooled, inv_n);

    // ---- MLP head ----
    k_mlp1<<<GG, H, 0, stream>>>(pooled, Wl1, bl1, z);
    k_zstats<<<1, H, 0, stream>>>(z, zst);
    k_mlp2<<<GG, H, 0, stream>>>(z, zst, gl, btl, Wl2, bl2, out);
}

// Round 7
// 704.395 us; speedup vs baseline: 1.6287x; 1.0572x over previous
//
#include <hip/hip_runtime.h>
#include <math.h>

#define NN 100000
#define NE 1600000
#define H 128
#define LH 384
#define GG 512
#define CC 10
#define EPSBN 1e-5f
#define BSH 9  // bucket shift: 512 nodes per bucket

typedef __attribute__((ext_vector_type(4))) float f32x4;
typedef __attribute__((ext_vector_type(8))) short s16x8;
typedef unsigned long long u64;

__device__ inline ushort f2b(float f) {
    uint u = __float_as_uint(f);
    uint r = (u + 0x7FFFu + ((u >> 16) & 1u)) >> 16;
    return (ushort)r;
}
__device__ inline float b2f(ushort b) { return __uint_as_float(((uint)b) << 16); }
__device__ inline float blo(uint v) { return __uint_as_float(v << 16); }
__device__ inline float bhi(uint v) { return __uint_as_float(v & 0xFFFF0000u); }

// ---------------- W transpose + bf16 convert: WT[j*128+k] = W[k*128+j] ------

__global__ void k_wt(const float* __restrict__ W, ushort* __restrict__ WT, int nmat) {
    int mat = blockIdx.x >> 7;
    int k = blockIdx.x & 127;
    int j = threadIdx.x;  // 128 threads
    WT[(size_t)mat * H * H + j * H + k] = f2b(W[(size_t)mat * H * H + k * H + j]);
}

// ---------------- bucketed CSR build ----------------

__global__ void k_bhist(const int* __restrict__ dst, int* __restrict__ bhist,
                        int e, int nbuck) {
    __shared__ int lh[256];
    lh[threadIdx.x] = 0;
    __syncthreads();
    int stride = gridDim.x * 256;
    for (int i = blockIdx.x * 256 + threadIdx.x; i < e; i += stride)
        atomicAdd(&lh[dst[i] >> BSH], 1);
    __syncthreads();
    int v = lh[threadIdx.x];
    if (threadIdx.x < nbuck && v) atomicAdd(&bhist[threadIdx.x], v);
}

__global__ void k_bscan(const int* __restrict__ bhist, int* __restrict__ bbase,
                        int* __restrict__ bcursor, int nbuck) {
    __shared__ int sh[256];
    int t = threadIdx.x;
    int v = (t < nbuck) ? bhist[t] : 0;
    sh[t] = v;
    __syncthreads();
    for (int off = 1; off < 256; off <<= 1) {
        int x = (t >= off) ? sh[t - off] : 0;
        __syncthreads();
        sh[t] += x;
        __syncthreads();
    }
    int run = sh[t] - v;
    if (t < nbuck) { bbase[t] = run; bcursor[t] = run; }
    if (t == nbuck) bbase[t] = run;
    if (t == 255 && nbuck > 255) bbase[nbuck] = sh[255];
}

// block-aggregated scatter: LDS histogram -> 1 global atomic per (block,bucket)
// packed u32 record: (dst & 511) << 17 | src
__global__ void k_bin(const int* __restrict__ src, const int* __restrict__ dst,
                      int* __restrict__ bcursor, uint* __restrict__ ebuf, int e) {
    __shared__ int lh[256], gb[256], lcur[256];
    int t = threadIdx.x;
    int base = blockIdx.x * 4096;
    int lim = e - base; if (lim > 4096) lim = 4096;
    lh[t] = 0;
    __syncthreads();
    for (int i = t; i < lim; i += 256)
        atomicAdd(&lh[dst[base + i] >> BSH], 1);
    __syncthreads();
    int c = lh[t];
    if (c) gb[t] = atomicAdd(&bcursor[t], c);
    lcur[t] = 0;
    __syncthreads();
    for (int i = t; i < lim; i += 256) {
        int s = src[base + i], d = dst[base + i];
        int b = d >> BSH;
        int p = atomicAdd(&lcur[b], 1);
        ebuf[(size_t)gb[b] + p] = ((uint)(d & 511) << 17) | (uint)s;
    }
}

__global__ void k_bfinal(const uint* __restrict__ ebuf, const int* __restrict__ bbase,
                         int* __restrict__ rp, float* __restrict__ dinv,
                         int* __restrict__ col, int n, int e) {
    __shared__ int hcnt[512], hoff[512], hcur[512];
    int b = blockIdx.x, t = threadIdx.x;
    int node0 = b << BSH;
    int e0 = bbase[b], e1 = bbase[b + 1];
    int m = e1 - e0;
    for (int j = t; j < 512; j += 256) hcnt[j] = 0;
    __syncthreads();
    for (int i = t; i < m; i += 256)
        atomicAdd(&hcnt[ebuf[e0 + i] >> 17], 1);
    __syncthreads();
    if (t == 0) {
        int run = 0;
        for (int j = 0; j < 512; ++j) { hoff[j] = run; run += hcnt[j]; }
    }
    __syncthreads();
    for (int j = t; j < 512; j += 256) {
        int node = node0 + j;
        if (node < n) {
            rp[node] = e0 + hoff[j];
            dinv[node] = rsqrtf((float)(hcnt[j] + 1));
        }
        hcur[j] = hoff[j];
    }
    if (b == 0 && t == 0) rp[n] = e;
    __syncthreads();
    for (int i = t; i < m; i += 256) {
        uint u = ebuf[e0 + i];
        int p = atomicAdd(&hcur[u >> 17], 1);
        col[e0 + p] = (int)(u & 0x1FFFFu);
    }
}

// ---------------- edge records: (dinv[src] bits << 32) | src ----------------

__global__ void k_erec(const int* __restrict__ col, const float* __restrict__ dinv,
                       u64* __restrict__ erec, int e) {
    int i = blockIdx.x * 256 + threadIdx.x;
    if (i < e) {
        int s = col[i];
        erec[i] = ((u64)__float_as_uint(dinv[s]) << 32) | (uint)s;
    }
}

// ---------------- MFMA GEMM: C[n,128]bf16 = BNReLU(A)[n,128] @ W ----------
// MODE 0: A fp32 raw (layer 0). MODE 1: A bf16 + fused BN+ReLU (layers 1,2).

template <int MODE>
__global__ __launch_bounds__(256) void k_gemm(
    const void* __restrict__ Ap, const ushort* __restrict__ WT,
    const float* __restrict__ stats, const float* __restrict__ g,
    const float* __restrict__ bt, float inv_n,
    ushort* __restrict__ Cout, int n) {
    __shared__ ushort As[64][136];
    __shared__ ushort Ws[128][136];
    __shared__ float bsc[128], bshf[128];
    int t = threadIdx.x;
    int wave = t >> 6, lane = t & 63;
    int rowBase = blockIdx.x * 64;

    if (MODE == 1) {
        if (t < 128) {
            float mu = stats[t] * inv_n;
            float var = stats[128 + t] * inv_n - mu * mu;
            float sc = g[t] * rsqrtf(var + EPSBN);
            bsc[t] = sc;
            bshf[t] = bt[t] - mu * sc;
        }
        __syncthreads();
    }

    if (MODE == 0) {
        const float* A = (const float*)Ap;
        for (int i = t; i < 64 * 32; i += 256) {
            int r = i >> 5, c4 = i & 31;
            int row = rowBase + r;
            float4 v = make_float4(0.f, 0.f, 0.f, 0.f);
            if (row < n) v = *(const float4*)(A + (size_t)row * H + c4 * 4);
            ushort4 o;
            o.x = f2b(v.x); o.y = f2b(v.y); o.z = f2b(v.z); o.w = f2b(v.w);
            *(ushort4*)(&As[r][c4 * 4]) = o;
        }
    } else {
        const ushort* A = (const ushort*)Ap;
        for (int i = t; i < 64 * 16; i += 256) {
            int r = i >> 4, c8 = i & 15;
            int row = rowBase + r;
            uint4 v = make_uint4(0u, 0u, 0u, 0u);
            if (row < n) v = *(const uint4*)(A + (size_t)row * H + c8 * 8);
            const uint* pv = (const uint*)&v;
            ushort o[8];
#pragma unroll
            for (int j = 0; j < 4; ++j) {
                int f0 = c8 * 8 + 2 * j;
                float v0 = fmaxf(fmaf(blo(pv[j]), bsc[f0], bshf[f0]), 0.f);
                float v1 = fmaxf(fmaf(bhi(pv[j]), bsc[f0 + 1], bshf[f0 + 1]), 0.f);
                o[2 * j] = f2b(v0);
                o[2 * j + 1] = f2b(v1);
            }
            *(uint4*)(&As[r][c8 * 8]) = *(const uint4*)o;
        }
    }
    for (int i = t; i < 128 * 16; i += 256) {
        int j = i >> 4, c8 = i & 15;
        uint4 v = *(const uint4*)(WT + j * H + c8 * 8);
        *(uint4*)(&Ws[j][c8 * 8]) = v;
    }
    __syncthreads();

    int m = lane & 15, q = lane >> 4;
    f32x4 acc[8];
#pragma unroll
    for (int c = 0; c < 8; ++c) acc[c] = (f32x4){0.f, 0.f, 0.f, 0.f};
#pragma unroll
    for (int kc = 0; kc < 4; ++kc) {
        int kof = kc * 32 + q * 8;
        s16x8 afrag = *(const s16x8*)(&As[wave * 16 + m][kof]);
#pragma unroll
        for (int c = 0; c < 8; ++c) {
            s16x8 bfrag = *(const s16x8*)(&Ws[c * 16 + m][kof]);
            acc[c] = __builtin_amdgcn_mfma_f32_16x16x32_bf16(afrag, bfrag, acc[c], 0, 0, 0);
        }
    }
#pragma unroll
    for (int c = 0; c < 8; ++c) {
        int colI = c * 16 + m;
#pragma unroll
        for (int r = 0; r < 4; ++r) {
            int row = rowBase + wave * 16 + q * 4 + r;
            if (row < n) Cout[(size_t)row * H + colI] = f2b(acc[c][r]);
        }
    }
}

// ---------------- Aggregation + fused BN stats (feature-split) ----------------
// block covers HALF a row (64 feats = 128 B); half = blockIdx&1 so all blocks
// on one XCD (round-robin dispatch) share a half -> per-XCD working set 12.8 MB.
// 8 subgroups x 8 lanes; 4-deep unroll = 32 half-rows in flight per wave.

__global__ __launch_bounds__(256) void k_agg(
    const ushort* __restrict__ hwb, const int* __restrict__ rp,
    const u64* __restrict__ erec, const float* __restrict__ dinv,
    float* __restrict__ stats, ushort* __restrict__ aggb, int n) {
    __shared__ float red[4][64];
    int wave = threadIdx.x >> 6, lane = threadIdx.x & 63;
    int sub = lane >> 3, sl = lane & 7;      // 8 subgroups of 8 lanes
    int half = blockIdx.x & 1;
    int fOff = half * 8;                      // uint4 offset within row (16 total)
    int nodeBase = (blockIdx.x >> 1) * 64 + wave * 16;
    const uint4* hw4 = (const uint4*)hwb;
    uint4* agg4 = (uint4*)aggb;
    float st_s[8], st_q[8];
#pragma unroll
    for (int j = 0; j < 8; ++j) { st_s[j] = 0.f; st_q[j] = 0.f; }

    for (int ni = 0; ni < 16; ++ni) {
        int node = nodeBase + ni;
        if (node >= n) break;
        float dn = dinv[node];
        float acc[8];
        if (sub == 0) {
            uint4 v = hw4[(size_t)node * 16 + fOff + sl];
            const uint* pv = (const uint*)&v;
#pragma unroll
            for (int j = 0; j < 4; ++j) {
                acc[2 * j] = dn * blo(pv[j]);
                acc[2 * j + 1] = dn * bhi(pv[j]);
            }
        } else {
#pragma unroll
            for (int j = 0; j < 8; ++j) acc[j] = 0.f;
        }
        int s0 = rp[node], s1 = rp[node + 1];
        for (int p = s0; p < s1; p += 32) {
            int eb = p + sub * 4;
            int i0 = eb < s1 ? eb : s1 - 1;
            int i1 = eb + 1 < s1 ? eb + 1 : s1 - 1;
            int i2 = eb + 2 < s1 ? eb + 2 : s1 - 1;
            int i3 = eb + 3 < s1 ? eb + 3 : s1 - 1;
            u64 r0 = erec[i0], r1 = erec[i1], r2 = erec[i2], r3 = erec[i3];
            float w0 = (eb < s1) ? __uint_as_float((uint)(r0 >> 32)) : 0.f;
            float w1 = (eb + 1 < s1) ? __uint_as_float((uint)(r1 >> 32)) : 0.f;
            float w2 = (eb + 2 < s1) ? __uint_as_float((uint)(r2 >> 32)) : 0.f;
            float w3 = (eb + 3 < s1) ? __uint_as_float((uint)(r3 >> 32)) : 0.f;
            uint4 v0 = hw4[(size_t)(uint)r0 * 16 + fOff + sl];
            uint4 v1 = hw4[(size_t)(uint)r1 * 16 + fOff + sl];
            uint4 v2 = hw4[(size_t)(uint)r2 * 16 + fOff + sl];
            uint4 v3 = hw4[(size_t)(uint)r3 * 16 + fOff + sl];
            const uint* p0 = (const uint*)&v0;
            const uint* p1 = (const uint*)&v1;
            const uint* p2 = (const uint*)&v2;
            const uint* p3 = (const uint*)&v3;
#pragma unroll
            for (int j = 0; j < 4; ++j) {
                acc[2 * j]     += w0 * blo(p0[j]) + w1 * blo(p1[j])
                                + w2 * blo(p2[j]) + w3 * blo(p3[j]);
                acc[2 * j + 1] += w0 * bhi(p0[j]) + w1 * bhi(p1[j])
                                + w2 * bhi(p2[j]) + w3 * bhi(p3[j]);
            }
        }
#pragma unroll
        for (int j = 0; j < 8; ++j) {
            acc[j] += __shfl_xor(acc[j], 8);
            acc[j] += __shfl_xor(acc[j], 16);
            acc[j] += __shfl_xor(acc[j], 32);
            acc[j] *= dn;
        }
        if (sub == 0) {
            uint4 o;
            uint* po = (uint*)&o;
#pragma unroll
            for (int j = 0; j < 4; ++j)
                po[j] = (uint)f2b(acc[2 * j]) | ((uint)f2b(acc[2 * j + 1]) << 16);
            agg4[(size_t)node * 16 + fOff + sl] = o;
#pragma unroll
            for (int j = 0; j < 8; ++j) {
                st_s[j] += acc[j];
                st_q[j] += acc[j] * acc[j];
            }
        }
    }
    if (sub == 0)
#pragma unroll
        for (int j = 0; j < 8; ++j) red[wave][sl * 8 + j] = st_s[j];
    __syncthreads();
    if (threadIdx.x < 64) {
        int f = threadIdx.x;
        atomicAdd(&stats[half * 64 + f], red[0][f] + red[1][f] + red[2][f] + red[3][f]);
    }
    __syncthreads();
    if (sub == 0)
#pragma unroll
        for (int j = 0; j < 8; ++j) red[wave][sl * 8 + j] = st_q[j];
    __syncthreads();
    if (threadIdx.x < 64) {
        int f = threadIdx.x;
        atomicAdd(&stats[128 + half * 64 + f], red[0][f] + red[1][f] + red[2][f] + red[3][f]);
    }
}

// ---------------- Pooling (BN+ReLU applied inline) ----------------

__global__ void k_gbound(const int* __restrict__ batch, int* __restrict__ gptr, int n) {
    int g = blockIdx.x * 256 + threadIdx.x;
    if (g > GG) return;
    int lo = 0, hi = n;
    while (lo < hi) {
        int mid = (lo + hi) >> 1;
        if (batch[mid] < g) lo = mid + 1; else hi = mid;
    }
    gptr[g] = lo;
}

__global__ void k_pool(const ushort* __restrict__ aggall, const float* __restrict__ statsall,
                       const float* __restrict__ g1, const float* __restrict__ bt1,
                       const float* __restrict__ gc, const float* __restrict__ btc,
                       const int* __restrict__ gptr, float* __restrict__ pooled,
                       float inv_n) {
    int g = blockIdx.x;
    int f = threadIdx.x;  // 384 threads
    int sec = f >> 7, feat = f & 127;
    const float* st = statsall + sec * 256;
    float mu = st[feat] * inv_n;
    float var = st[128 + feat] * inv_n - mu * mu;
    float gm = (sec == 0) ? g1[feat] : gc[(sec - 1) * H + feat];
    float bm = (sec == 0) ? bt1[feat] : btc[(sec - 1) * H + feat];
    float sc = gm * rsqrtf(var + EPSBN);
    float sh = bm - mu * sc;
    const ushort* a = aggall + (size_t)sec * NN * H;
    int r0 = gptr[g], r1 = gptr[g + 1];
    float s = 0.f;
    for (int r = r0; r < r1; ++r)
        s += fmaxf(fmaf(b2f(a[(size_t)r * H + feat]), sc, sh), 0.f);
    float c = (float)(r1 - r0);
    pooled[g * LH + f] = s / fmaxf(c, 1.f);
}

// ---------------- MLP head ----------------

__global__ void k_mlp1(const float* __restrict__ pooled, const float* __restrict__ Wl1,
                       const float* __restrict__ bl1, float* __restrict__ z) {
    __shared__ float row[LH];
    int g = blockIdx.x;
    int j = threadIdx.x;  // 128 threads
    for (int k = j; k < LH; k += H) row[k] = pooled[g * LH + k];
    __syncthreads();
    float acc = bl1[j];
    for (int k = 0; k < LH; ++k) acc += row[k] * Wl1[k * H + j];
    z[g * H + j] = acc;
}

__global__ void k_zstats(const float* __restrict__ z, float* __restrict__ st) {
    int j = threadIdx.x;  // 128 threads, 1 block
    float s = 0.f, q = 0.f;
    for (int g = 0; g < GG; ++g) {
        float v = z[g * H + j];
        s += v;
        q += v * v;
    }
    st[j] = s;
    st[128 + j] = q;
}

__global__ void k_mlp2(const float* __restrict__ z, const float* __restrict__ st,
                       const float* __restrict__ gl, const float* __restrict__ btl,
                       const float* __restrict__ Wl2, const float* __restrict__ bl2,
                       float* __restrict__ out) {
    __shared__ float zn[H];
    __shared__ float logit[CC];
    int g = blockIdx.x;
    int t = threadIdx.x;  // 128 threads
    float mu = st[t] * (1.f / GG);
    float var = st[128 + t] * (1.f / GG) - mu * mu;
    float v = (z[g * H + t] - mu) * rsqrtf(var + EPSBN) * gl[t] + btl[t];
    zn[t] = fmaxf(v, 0.f);
    __syncthreads();
    if (t < CC) {
        float acc = bl2[t];
        for (int k = 0; k < H; ++k) acc += zn[k] * Wl2[k * CC + t];
        logit[t] = acc;
    }
    __syncthreads();
    if (t == 0) {
        float m = -1e30f;
        for (int c = 0; c < CC; ++c) m = fmaxf(m, logit[c]);
        float se = 0.f;
        for (int c = 0; c < CC; ++c) se += expf(logit[c] - m);
        float lse = m + logf(se);
        for (int c = 0; c < CC; ++c) out[g * CC + c] = logit[c] - lse;
    }
}

// ---------------- launch ----------------

extern "C" void kernel_launch(void* const* d_in, const int* in_sizes, int n_in,
                              void* d_out, int out_size, void* d_ws, size_t ws_size,
                              hipStream_t stream) {
    const float* x   = (const float*)d_in[0];
    const int*   ei  = (const int*)d_in[1];
    const int*   bat = (const int*)d_in[2];
    const float* W1  = (const float*)d_in[3];
    const float* g1  = (const float*)d_in[5];
    const float* bt1 = (const float*)d_in[6];
    const float* Wc  = (const float*)d_in[7];
    const float* gc  = (const float*)d_in[9];
    const float* btc = (const float*)d_in[10];
    const float* Wl1 = (const float*)d_in[11];
    const float* bl1 = (const float*)d_in[12];
    const float* gl  = (const float*)d_in[13];
    const float* btl = (const float*)d_in[14];
    const float* Wl2 = (const float*)d_in[15];
    const float* bl2 = (const float*)d_in[16];
    float* out = (float*)d_out;

    const int n = in_sizes[2];
    const int e = in_sizes[1] / 2;
    const int* src = ei;
    const int* dst = ei + e;
    const int nbuck = (n + 511) / 512;  // <= 256
    const float inv_n = 1.0f / (float)n;

    size_t off = 0;
    char* base = (char*)d_ws;
    auto take = [&](size_t nbytes) -> void* {
        void* p = base + off;
        off += (nbytes + 255) & ~(size_t)255;
        return p;
    };
    int*    rp      = (int*)take((size_t)(NN + 1) * 4);
    int*    col     = (int*)take((size_t)NE * 4);
    float*  dinv    = (float*)take((size_t)NN * 4);
    int*    bhist   = (int*)take(1024 + 8);
    int*    bbase   = (int*)take(1024 + 8);
    int*    bcursor = (int*)take(1024 + 8);
    uint*   ebuf    = (uint*)take((size_t)NE * 4);
    u64*    erec    = (u64*)take((size_t)NE * 8);
    float*  stats   = (float*)take(3 * 1024);
    int*    gptr    = (int*)take((size_t)(GG + 1) * 4);
    ushort* WTb     = (ushort*)take((size_t)3 * H * H * 2);
    ushort* hwb     = (ushort*)take((size_t)NN * H * 2);
    ushort* aggb    = (ushort*)take((size_t)3 * NN * H * 2);
    float*  pooled  = (float*)take((size_t)GG * LH * 4);
    float*  z       = (float*)take((size_t)GG * H * 4);
    float*  zst     = (float*)take(1024);

    // ---- weight transpose/convert ----
    k_wt<<<H, H, 0, stream>>>(W1, WTb, 1);
    k_wt<<<2 * H, H, 0, stream>>>(Wc, WTb + (size_t)H * H, 2);

    // ---- bucketed CSR build ----
    hipMemsetAsync(bhist, 0, 1024 + 8, stream);
    k_bhist<<<256, 256, 0, stream>>>(dst, bhist, e, nbuck);
    k_bscan<<<1, 256, 0, stream>>>(bhist, bbase, bcursor, nbuck);
    k_bin<<<(e + 4095) / 4096, 256, 0, stream>>>(src, dst, bcursor, ebuf, e);
    k_bfinal<<<nbuck, 256, 0, stream>>>(ebuf, bbase, rp, dinv, col, n, e);
    k_erec<<<(e + 255) / 256, 256, 0, stream>>>(col, dinv, erec, e);

    // ---- 3 GCN layers (BN+ReLU of layer l-1 fused into layer l's GEMM) ----
    hipMemsetAsync(stats, 0, 3 * 1024, stream);
    for (int l = 0; l < 3; ++l) {
        const ushort* WT = WTb + (size_t)l * H * H;

        if (l == 0) {
            k_gemm<0><<<(n + 63) / 64, 256, 0, stream>>>(
                x, WT, nullptr, nullptr, nullptr, inv_n, hwb, n);
        } else {
            const float* gm  = (l == 1) ? g1 : gc;
            const float* btm = (l == 1) ? bt1 : btc;
            k_gemm<1><<<(n + 63) / 64, 256, 0, stream>>>(
                aggb + (size_t)(l - 1) * NN * H, WT, stats + (size_t)(l - 1) * 256,
                gm, btm, inv_n, hwb, n);
        }
        k_agg<<<((n + 63) / 64) * 2, 256, 0, stream>>>(
            hwb, rp, erec, dinv, stats + (size_t)l * 256, aggb + (size_t)l * NN * H, n);
    }

    // ---- pooling ----
    k_gbound<<<3, 256, 0, stream>>>(bat, gptr, n);
    k_pool<<<GG, LH, 0, stream>>>(aggb, stats, g1, bt1, gc, btc, gptr, pooled, inv_n);

    // ---- MLP head ----
    k_mlp1<<<GG, H, 0, stream>>>(pooled, Wl1, bl1, z);
    k_zstats<<<1, H, 0, stream>>>(z, zst);
    k_mlp2<<<GG, H, 0, stream>>>(z, zst, gl, btl, Wl2, bl2, out);
}

// Round 8
// 656.177 us; speedup vs baseline: 1.7484x; 1.0735x over previous
//
#include <hip/hip_runtime.h>
#include <math.h>

#define NN 100000
#define NE 1600000
#define H 128
#define LH 384
#define GG 512
#define CC 10
#define EPSBN 1e-5f
#define BSH 9  // bucket shift: 512 nodes per bucket

typedef __attribute__((ext_vector_type(4))) float f32x4;
typedef __attribute__((ext_vector_type(2))) float f32x2;
typedef __attribute__((ext_vector_type(8))) short s16x8;
typedef unsigned long long u64;

__device__ inline ushort f2b(float f) {
    uint u = __float_as_uint(f);
    uint r = (u + 0x7FFFu + ((u >> 16) & 1u)) >> 16;
    return (ushort)r;
}
__device__ inline float b2f(ushort b) { return __uint_as_float(((uint)b) << 16); }
__device__ inline float blo(uint v) { return __uint_as_float(v << 16); }
__device__ inline float bhi(uint v) { return __uint_as_float(v & 0xFFFF0000u); }

// ---------------- W transpose + bf16 convert: WT[j*128+k] = W[k*128+j] ------

__global__ void k_wt(const float* __restrict__ W, ushort* __restrict__ WT, int nmat) {
    int mat = blockIdx.x >> 7;
    int k = blockIdx.x & 127;
    int j = threadIdx.x;  // 128 threads
    WT[(size_t)mat * H * H + j * H + k] = f2b(W[(size_t)mat * H * H + k * H + j]);
}

// ---------------- bucketed CSR build ----------------

__global__ void k_bhist(const int* __restrict__ dst, int* __restrict__ bhist,
                        int e, int nbuck) {
    __shared__ int lh[256];
    lh[threadIdx.x] = 0;
    __syncthreads();
    int stride = gridDim.x * 256;
    for (int i = blockIdx.x * 256 + threadIdx.x; i < e; i += stride)
        atomicAdd(&lh[dst[i] >> BSH], 1);
    __syncthreads();
    int v = lh[threadIdx.x];
    if (threadIdx.x < nbuck && v) atomicAdd(&bhist[threadIdx.x], v);
}

__global__ void k_bscan(const int* __restrict__ bhist, int* __restrict__ bbase,
                        int* __restrict__ bcursor, int nbuck) {
    __shared__ int sh[256];
    int t = threadIdx.x;
    int v = (t < nbuck) ? bhist[t] : 0;
    sh[t] = v;
    __syncthreads();
    for (int off = 1; off < 256; off <<= 1) {
        int x = (t >= off) ? sh[t - off] : 0;
        __syncthreads();
        sh[t] += x;
        __syncthreads();
    }
    int run = sh[t] - v;
    if (t < nbuck) { bbase[t] = run; bcursor[t] = run; }
    if (t == nbuck) bbase[t] = run;
    if (t == 255 && nbuck > 255) bbase[nbuck] = sh[255];
}

// block-aggregated scatter: LDS histogram -> 1 global atomic per (block,bucket)
// packed u32 record: (dst & 511) << 17 | src
__global__ void k_bin(const int* __restrict__ src, const int* __restrict__ dst,
                      int* __restrict__ bcursor, uint* __restrict__ ebuf, int e) {
    __shared__ int lh[256], gb[256], lcur[256];
    int t = threadIdx.x;
    int base = blockIdx.x * 4096;
    int lim = e - base; if (lim > 4096) lim = 4096;
    lh[t] = 0;
    __syncthreads();
    for (int i = t; i < lim; i += 256)
        atomicAdd(&lh[dst[base + i] >> BSH], 1);
    __syncthreads();
    int c = lh[t];
    if (c) gb[t] = atomicAdd(&bcursor[t], c);
    lcur[t] = 0;
    __syncthreads();
    for (int i = t; i < lim; i += 256) {
        int s = src[base + i], d = dst[base + i];
        int b = d >> BSH;
        int p = atomicAdd(&lcur[b], 1);
        ebuf[(size_t)gb[b] + p] = ((uint)(d & 511) << 17) | (uint)s;
    }
}

__global__ void k_bfinal(const uint* __restrict__ ebuf, const int* __restrict__ bbase,
                         int* __restrict__ rp, float* __restrict__ dinv,
                         int* __restrict__ col, int n, int e) {
    __shared__ int hcnt[512], hoff[512], hcur[512];
    int b = blockIdx.x, t = threadIdx.x;
    int node0 = b << BSH;
    int e0 = bbase[b], e1 = bbase[b + 1];
    int m = e1 - e0;
    for (int j = t; j < 512; j += 256) hcnt[j] = 0;
    __syncthreads();
    for (int i = t; i < m; i += 256)
        atomicAdd(&hcnt[ebuf[e0 + i] >> 17], 1);
    __syncthreads();
    if (t == 0) {
        int run = 0;
        for (int j = 0; j < 512; ++j) { hoff[j] = run; run += hcnt[j]; }
    }
    __syncthreads();
    for (int j = t; j < 512; j += 256) {
        int node = node0 + j;
        if (node < n) {
            rp[node] = e0 + hoff[j];
            dinv[node] = rsqrtf((float)(hcnt[j] + 1));
        }
        hcur[j] = hoff[j];
    }
    if (b == 0 && t == 0) rp[n] = e;
    __syncthreads();
    for (int i = t; i < m; i += 256) {
        uint u = ebuf[e0 + i];
        int p = atomicAdd(&hcur[u >> 17], 1);
        col[e0 + p] = (int)(u & 0x1FFFFu);
    }
}

// ---------------- edge records: u32 = dinv[src] top-15 bits | src (17 bits) --

__global__ void k_erec(const int* __restrict__ col, const float* __restrict__ dinv,
                       uint* __restrict__ erec, int e) {
    int i = blockIdx.x * 256 + threadIdx.x;
    if (i < e) {
        int s = col[i];
        uint db = __float_as_uint(dinv[s]);
        erec[i] = ((db + 0x10000u) & 0xFFFE0000u) | (uint)s;  // round-to-nearest 15-bit
    }
}

// ---------------- MFMA GEMM: C = BNReLU(A)[n,128] @ W, quarter-planar out ---
// MODE 0: A fp32 raw (layer 0). MODE 1: A bf16 + fused BN+ReLU (layers 1,2).
// Output hwq: quarter q of row r at hwq[(q*NN + r)*32 + (col&31)].

template <int MODE>
__global__ __launch_bounds__(256) void k_gemm(
    const void* __restrict__ Ap, const ushort* __restrict__ WT,
    const float* __restrict__ stats, const float* __restrict__ g,
    const float* __restrict__ bt, float inv_n,
    ushort* __restrict__ Cout, int n) {
    __shared__ ushort As[64][136];
    __shared__ ushort Ws[128][136];
    __shared__ float bsc[128], bshf[128];
    int t = threadIdx.x;
    int wave = t >> 6, lane = t & 63;
    int rowBase = blockIdx.x * 64;

    if (MODE == 1) {
        if (t < 128) {
            float mu = stats[t] * inv_n;
            float var = stats[128 + t] * inv_n - mu * mu;
            float sc = g[t] * rsqrtf(var + EPSBN);
            bsc[t] = sc;
            bshf[t] = bt[t] - mu * sc;
        }
        __syncthreads();
    }

    if (MODE == 0) {
        const float* A = (const float*)Ap;
        for (int i = t; i < 64 * 32; i += 256) {
            int r = i >> 5, c4 = i & 31;
            int row = rowBase + r;
            float4 v = make_float4(0.f, 0.f, 0.f, 0.f);
            if (row < n) v = *(const float4*)(A + (size_t)row * H + c4 * 4);
            ushort4 o;
            o.x = f2b(v.x); o.y = f2b(v.y); o.z = f2b(v.z); o.w = f2b(v.w);
            *(ushort4*)(&As[r][c4 * 4]) = o;
        }
    } else {
        const ushort* A = (const ushort*)Ap;
        for (int i = t; i < 64 * 16; i += 256) {
            int r = i >> 4, c8 = i & 15;
            int row = rowBase + r;
            uint4 v = make_uint4(0u, 0u, 0u, 0u);
            if (row < n) v = *(const uint4*)(A + (size_t)row * H + c8 * 8);
            const uint* pv = (const uint*)&v;
            ushort o[8];
#pragma unroll
            for (int j = 0; j < 4; ++j) {
                int f0 = c8 * 8 + 2 * j;
                float v0 = fmaxf(fmaf(blo(pv[j]), bsc[f0], bshf[f0]), 0.f);
                float v1 = fmaxf(fmaf(bhi(pv[j]), bsc[f0 + 1], bshf[f0 + 1]), 0.f);
                o[2 * j] = f2b(v0);
                o[2 * j + 1] = f2b(v1);
            }
            *(uint4*)(&As[r][c8 * 8]) = *(const uint4*)o;
        }
    }
    for (int i = t; i < 128 * 16; i += 256) {
        int j = i >> 4, c8 = i & 15;
        uint4 v = *(const uint4*)(WT + j * H + c8 * 8);
        *(uint4*)(&Ws[j][c8 * 8]) = v;
    }
    __syncthreads();

    int m = lane & 15, qd = lane >> 4;
    f32x4 acc[8];
#pragma unroll
    for (int c = 0; c < 8; ++c) acc[c] = (f32x4){0.f, 0.f, 0.f, 0.f};
#pragma unroll
    for (int kc = 0; kc < 4; ++kc) {
        int kof = kc * 32 + qd * 8;
        s16x8 afrag = *(const s16x8*)(&As[wave * 16 + m][kof]);
#pragma unroll
        for (int c = 0; c < 8; ++c) {
            s16x8 bfrag = *(const s16x8*)(&Ws[c * 16 + m][kof]);
            acc[c] = __builtin_amdgcn_mfma_f32_16x16x32_bf16(afrag, bfrag, acc[c], 0, 0, 0);
        }
    }
#pragma unroll
    for (int c = 0; c < 8; ++c) {
        int colI = c * 16 + m;
        int qq = colI >> 5, cq = colI & 31;
#pragma unroll
        for (int r = 0; r < 4; ++r) {
            int row = rowBase + wave * 16 + qd * 4 + r;
            if (row < n) Cout[((size_t)qq * NN + row) * 32 + cq] = f2b(acc[c][r]);
        }
    }
}

// ---------------- Aggregation + fused BN stats (quarter-split, per-sub nodes)
// 4-lane subgroup <-> 64 B quarter-row; sub owns whole nodes via LDS cursor;
// 4-deep per-sub unroll (waste ~1.5 gathers/node). quarter = blockIdx&3 so
// each XCD (blockIdx%8) sees one quarter -> 6.4 MB working set.

__global__ __launch_bounds__(256) void k_agg(
    const ushort* __restrict__ hwq, const int* __restrict__ rp,
    const uint* __restrict__ erec, const float* __restrict__ dinv,
    float* __restrict__ stats, ushort* __restrict__ aggb, int n) {
    __shared__ int cursor;
    __shared__ float lsum[32], lsq[32];
    int t = threadIdx.x;
    int lane = t & 63;
    int sl = lane & 3;
    int sub0 = lane & ~3;
    int q = blockIdx.x & 3;
    int nodeBase = (blockIdx.x >> 2) * 256;
    if (t == 0) cursor = 0;
    if (t < 32) { lsum[t] = 0.f; lsq[t] = 0.f; }
    __syncthreads();
    const uint4* hw4 = (const uint4*)hwq;  // planar: (q*NN + node)*4 + sl
    uint4* agg4 = (uint4*)aggb;            // interleaved: node*16 + q*4 + sl
    f32x2 ss[4], sq[4];
#pragma unroll
    for (int j = 0; j < 4; ++j) { ss[j] = (f32x2){0.f, 0.f}; sq[j] = (f32x2){0.f, 0.f}; }

    for (;;) {
        int ni = 0;
        if (sl == 0) ni = atomicAdd(&cursor, 1);
        ni = __shfl(ni, sub0);
        int node = nodeBase + ni;
        if (ni >= 256 || node >= n) break;
        float dn = dinv[node];
        f32x2 acc[4];
        {
            uint4 v = hw4[((size_t)q * NN + node) * 4 + sl];
            const uint* pv = (const uint*)&v;
#pragma unroll
            for (int j = 0; j < 4; ++j)
                acc[j] = (f32x2){dn * blo(pv[j]), dn * bhi(pv[j])};
        }
        int p = rp[node], pe = rp[node + 1];
        for (; p < pe; p += 4) {
            int i1 = p + 1 < pe ? p + 1 : pe - 1;
            int i2 = p + 2 < pe ? p + 2 : pe - 1;
            int i3 = p + 3 < pe ? p + 3 : pe - 1;
            uint r0 = erec[p], r1 = erec[i1], r2 = erec[i2], r3 = erec[i3];
            float w0 = __uint_as_float(r0 & 0xFFFE0000u);
            float w1 = (p + 1 < pe) ? __uint_as_float(r1 & 0xFFFE0000u) : 0.f;
            float w2 = (p + 2 < pe) ? __uint_as_float(r2 & 0xFFFE0000u) : 0.f;
            float w3 = (p + 3 < pe) ? __uint_as_float(r3 & 0xFFFE0000u) : 0.f;
            uint4 v0 = hw4[((size_t)q * NN + (r0 & 0x1FFFFu)) * 4 + sl];
            uint4 v1 = hw4[((size_t)q * NN + (r1 & 0x1FFFFu)) * 4 + sl];
            uint4 v2 = hw4[((size_t)q * NN + (r2 & 0x1FFFFu)) * 4 + sl];
            uint4 v3 = hw4[((size_t)q * NN + (r3 & 0x1FFFFu)) * 4 + sl];
            const uint* p0 = (const uint*)&v0;
            const uint* p1 = (const uint*)&v1;
            const uint* p2 = (const uint*)&v2;
            const uint* p3 = (const uint*)&v3;
            f32x2 wv0 = (f32x2){w0, w0}, wv1 = (f32x2){w1, w1};
            f32x2 wv2 = (f32x2){w2, w2}, wv3 = (f32x2){w3, w3};
#pragma unroll
            for (int j = 0; j < 4; ++j) {
                acc[j] = __builtin_elementwise_fma(wv0, (f32x2){blo(p0[j]), bhi(p0[j])}, acc[j]);
                acc[j] = __builtin_elementwise_fma(wv1, (f32x2){blo(p1[j]), bhi(p1[j])}, acc[j]);
                acc[j] = __builtin_elementwise_fma(wv2, (f32x2){blo(p2[j]), bhi(p2[j])}, acc[j]);
                acc[j] = __builtin_elementwise_fma(wv3, (f32x2){blo(p3[j]), bhi(p3[j])}, acc[j]);
            }
        }
        uint4 o;
        uint* po = (uint*)&o;
        f32x2 dn2 = (f32x2){dn, dn};
#pragma unroll
        for (int j = 0; j < 4; ++j) {
            f32x2 ov = dn2 * acc[j];
            ss[j] += ov;
            sq[j] = __builtin_elementwise_fma(ov, ov, sq[j]);
            po[j] = (uint)f2b(ov.x) | ((uint)f2b(ov.y) << 16);
        }
        agg4[(size_t)node * 16 + q * 4 + sl] = o;
    }
#pragma unroll
    for (int j = 0; j < 4; ++j) {
        atomicAdd(&lsum[sl * 8 + 2 * j], ss[j].x);
        atomicAdd(&lsum[sl * 8 + 2 * j + 1], ss[j].y);
        atomicAdd(&lsq[sl * 8 + 2 * j], sq[j].x);
        atomicAdd(&lsq[sl * 8 + 2 * j + 1], sq[j].y);
    }
    __syncthreads();
    if (t < 32) {
        atomicAdd(&stats[q * 32 + t], lsum[t]);
        atomicAdd(&stats[128 + q * 32 + t], lsq[t]);
    }
}

// ---------------- Pooling (BN+ReLU applied inline) ----------------

__global__ void k_gbound(const int* __restrict__ batch, int* __restrict__ gptr, int n) {
    int g = blockIdx.x * 256 + threadIdx.x;
    if (g > GG) return;
    int lo = 0, hi = n;
    while (lo < hi) {
        int mid = (lo + hi) >> 1;
        if (batch[mid] < g) lo = mid + 1; else hi = mid;
    }
    gptr[g] = lo;
}

__global__ void k_pool(const ushort* __restrict__ aggall, const float* __restrict__ statsall,
                       const float* __restrict__ g1, const float* __restrict__ bt1,
                       const float* __restrict__ gc, const float* __restrict__ btc,
                       const int* __restrict__ gptr, float* __restrict__ pooled,
                       float inv_n) {
    int g = blockIdx.x;
    int f = threadIdx.x;  // 384 threads
    int sec = f >> 7, feat = f & 127;
    const float* st = statsall + sec * 256;
    float mu = st[feat] * inv_n;
    float var = st[128 + feat] * inv_n - mu * mu;
    float gm = (sec == 0) ? g1[feat] : gc[(sec - 1) * H + feat];
    float bm = (sec == 0) ? bt1[feat] : btc[(sec - 1) * H + feat];
    float sc = gm * rsqrtf(var + EPSBN);
    float sh = bm - mu * sc;
    const ushort* a = aggall + (size_t)sec * NN * H;
    int r0 = gptr[g], r1 = gptr[g + 1];
    float s = 0.f;
    for (int r = r0; r < r1; ++r)
        s += fmaxf(fmaf(b2f(a[(size_t)r * H + feat]), sc, sh), 0.f);
    float c = (float)(r1 - r0);
    pooled[g * LH + f] = s / fmaxf(c, 1.f);
}

// ---------------- MLP head ----------------

__global__ void k_mlp1(const float* __restrict__ pooled, const float* __restrict__ Wl1,
                       const float* __restrict__ bl1, float* __restrict__ z) {
    __shared__ float row[LH];
    int g = blockIdx.x;
    int j = threadIdx.x;  // 128 threads
    for (int k = j; k < LH; k += H) row[k] = pooled[g * LH + k];
    __syncthreads();
    float acc = bl1[j];
    for (int k = 0; k < LH; ++k) acc += row[k] * Wl1[k * H + j];
    z[g * H + j] = acc;
}

__global__ void k_zstats(const float* __restrict__ z, float* __restrict__ st) {
    int j = threadIdx.x;  // 128 threads, 1 block
    float s = 0.f, q = 0.f;
    for (int g = 0; g < GG; ++g) {
        float v = z[g * H + j];
        s += v;
        q += v * v;
    }
    st[j] = s;
    st[128 + j] = q;
}

__global__ void k_mlp2(const float* __restrict__ z, const float* __restrict__ st,
                       const float* __restrict__ gl, const float* __restrict__ btl,
                       const float* __restrict__ Wl2, const float* __restrict__ bl2,
                       float* __restrict__ out) {
    __shared__ float zn[H];
    __shared__ float logit[CC];
    int g = blockIdx.x;
    int t = threadIdx.x;  // 128 threads
    float mu = st[t] * (1.f / GG);
    float var = st[128 + t] * (1.f / GG) - mu * mu;
    float v = (z[g * H + t] - mu) * rsqrtf(var + EPSBN) * gl[t] + btl[t];
    zn[t] = fmaxf(v, 0.f);
    __syncthreads();
    if (t < CC) {
        float acc = bl2[t];
        for (int k = 0; k < H; ++k) acc += zn[k] * Wl2[k * CC + t];
        logit[t] = acc;
    }
    __syncthreads();
    if (t == 0) {
        float m = -1e30f;
        for (int c = 0; c < CC; ++c) m = fmaxf(m, logit[c]);
        float se = 0.f;
        for (int c = 0; c < CC; ++c) se += expf(logit[c] - m);
        float lse = m + logf(se);
        for (int c = 0; c < CC; ++c) out[g * CC + c] = logit[c] - lse;
    }
}

// ---------------- launch ----------------

extern "C" void kernel_launch(void* const* d_in, const int* in_sizes, int n_in,
                              void* d_out, int out_size, void* d_ws, size_t ws_size,
                              hipStream_t stream) {
    const float* x   = (const float*)d_in[0];
    const int*   ei  = (const int*)d_in[1];
    const int*   bat = (const int*)d_in[2];
    const float* W1  = (const float*)d_in[3];
    const float* g1  = (const float*)d_in[5];
    const float* bt1 = (const float*)d_in[6];
    const float* Wc  = (const float*)d_in[7];
    const float* gc  = (const float*)d_in[9];
    const float* btc = (const float*)d_in[10];
    const float* Wl1 = (const float*)d_in[11];
    const float* bl1 = (const float*)d_in[12];
    const float* gl  = (const float*)d_in[13];
    const float* btl = (const float*)d_in[14];
    const float* Wl2 = (const float*)d_in[15];
    const float* bl2 = (const float*)d_in[16];
    float* out = (float*)d_out;

    const int n = in_sizes[2];
    const int e = in_sizes[1] / 2;
    const int* src = ei;
    const int* dst = ei + e;
    const int nbuck = (n + 511) / 512;  // <= 256
    const float inv_n = 1.0f / (float)n;

    size_t off = 0;
    char* base = (char*)d_ws;
    auto take = [&](size_t nbytes) -> void* {
        void* p = base + off;
        off += (nbytes + 255) & ~(size_t)255;
        return p;
    };
    int*    rp      = (int*)take((size_t)(NN + 1) * 4);
    int*    col     = (int*)take((size_t)NE * 4);
    float*  dinv    = (float*)take((size_t)NN * 4);
    int*    bhist   = (int*)take(1024 + 8);
    int*    bbase   = (int*)take(1024 + 8);
    int*    bcursor = (int*)take(1024 + 8);
    uint*   ebuf    = (uint*)take((size_t)NE * 4);
    uint*   erec    = (uint*)take((size_t)NE * 4);
    float*  stats   = (float*)take(3 * 1024);
    int*    gptr    = (int*)take((size_t)(GG + 1) * 4);
    ushort* WTb     = (ushort*)take((size_t)3 * H * H * 2);
    ushort* hwb     = (ushort*)take((size_t)NN * H * 2);
    ushort* aggb    = (ushort*)take((size_t)3 * NN * H * 2);
    float*  pooled  = (float*)take((size_t)GG * LH * 4);
    float*  z       = (float*)take((size_t)GG * H * 4);
    float*  zst     = (float*)take(1024);

    // ---- weight transpose/convert ----
    k_wt<<<H, H, 0, stream>>>(W1, WTb, 1);
    k_wt<<<2 * H, H, 0, stream>>>(Wc, WTb + (size_t)H * H, 2);

    // ---- bucketed CSR build ----
    hipMemsetAsync(bhist, 0, 1024 + 8, stream);
    k_bhist<<<256, 256, 0, stream>>>(dst, bhist, e, nbuck);
    k_bscan<<<1, 256, 0, stream>>>(bhist, bbase, bcursor, nbuck);
    k_bin<<<(e + 4095) / 4096, 256, 0, stream>>>(src, dst, bcursor, ebuf, e);
    k_bfinal<<<nbuck, 256, 0, stream>>>(ebuf, bbase, rp, dinv, col, n, e);
    k_erec<<<(e + 255) / 256, 256, 0, stream>>>(col, dinv, erec, e);

    // ---- 3 GCN layers (BN+ReLU of layer l-1 fused into layer l's GEMM) ----
    hipMemsetAsync(stats, 0, 3 * 1024, stream);
    for (int l = 0; l < 3; ++l) {
        const ushort* WT = WTb + (size_t)l * H * H;

        if (l == 0) {
            k_gemm<0><<<(n + 63) / 64, 256, 0, stream>>>(
                x, WT, nullptr, nullptr, nullptr, inv_n, hwb, n);
        } else {
            const float* gm  = (l == 1) ? g1 : gc;
            const float* btm = (l == 1) ? bt1 : btc;
            k_gemm<1><<<(n + 63) / 64, 256, 0, stream>>>(
                aggb + (size_t)(l - 1) * NN * H, WT, stats + (size_t)(l - 1) * 256,
                gm, btm, inv_n, hwb, n);
        }
        k_agg<<<((n + 255) / 256) * 4, 256, 0, stream>>>(
            hwb, rp, erec, dinv, stats + (size_t)l * 256, aggb + (size_t)l * NN * H, n);
    }

    // ---- pooling ----
    k_gbound<<<3, 256, 0, stream>>>(bat, gptr, n);
    k_pool<<<GG, LH, 0, stream>>>(aggb, stats, g1, bt1, gc, btc, gptr, pooled, inv_n);

    // ---- MLP head ----
    k_mlp1<<<GG, H, 0, stream>>>(pooled, Wl1, bl1, z);
    k_zstats<<<1, H, 0, stream>>>(z, zst);
    k_mlp2<<<GG, H, 0, stream>>>(z, zst, gl, btl, Wl2, bl2, out);
}

// Round 9
// 596.322 us; speedup vs baseline: 1.9238x; 1.1004x over previous
//
#include <hip/hip_runtime.h>
#include <math.h>

#define NN 100000
#define NE 1600000
#define H 128
#define LH 384
#define GG 512
#define CC 10
#define EPSBN 1e-5f
#define BSH 9  // bucket shift: 512 nodes per bucket

typedef __attribute__((ext_vector_type(4))) float f32x4;
typedef __attribute__((ext_vector_type(2))) float f32x2;
typedef __attribute__((ext_vector_type(8))) short s16x8;
typedef unsigned long long u64;

__device__ inline ushort f2b(float f) {
    uint u = __float_as_uint(f);
    uint r = (u + 0x7FFFu + ((u >> 16) & 1u)) >> 16;
    return (ushort)r;
}
__device__ inline float b2f(ushort b) { return __uint_as_float(((uint)b) << 16); }
__device__ inline float blo(uint v) { return __uint_as_float(v << 16); }
__device__ inline float bhi(uint v) { return __uint_as_float(v & 0xFFFF0000u); }

// ---------------- W transpose + bf16 convert: WT[j*128+k] = W[k*128+j] ------

__global__ void k_wt(const float* __restrict__ W, ushort* __restrict__ WT, int nmat) {
    int mat = blockIdx.x >> 7;
    int k = blockIdx.x & 127;
    int j = threadIdx.x;  // 128 threads
    WT[(size_t)mat * H * H + j * H + k] = f2b(W[(size_t)mat * H * H + k * H + j]);
}

// ---------------- bucketed CSR build ----------------

__global__ void k_bhist(const int* __restrict__ dst, int* __restrict__ bhist,
                        int e, int nbuck) {
    __shared__ int lh[256];
    lh[threadIdx.x] = 0;
    __syncthreads();
    int stride = gridDim.x * 256;
    for (int i = blockIdx.x * 256 + threadIdx.x; i < e; i += stride)
        atomicAdd(&lh[dst[i] >> BSH], 1);
    __syncthreads();
    int v = lh[threadIdx.x];
    if (threadIdx.x < nbuck && v) atomicAdd(&bhist[threadIdx.x], v);
}

__global__ void k_bscan(const int* __restrict__ bhist, int* __restrict__ bbase,
                        int* __restrict__ bcursor, int nbuck) {
    __shared__ int sh[256];
    int t = threadIdx.x;
    int v = (t < nbuck) ? bhist[t] : 0;
    sh[t] = v;
    __syncthreads();
    for (int off = 1; off < 256; off <<= 1) {
        int x = (t >= off) ? sh[t - off] : 0;
        __syncthreads();
        sh[t] += x;
        __syncthreads();
    }
    int run = sh[t] - v;
    if (t < nbuck) { bbase[t] = run; bcursor[t] = run; }
    if (t == nbuck) bbase[t] = run;
    if (t == 255 && nbuck > 255) bbase[nbuck] = sh[255];
}

// block-aggregated scatter: LDS histogram -> 1 global atomic per (block,bucket)
// packed u32 record: (dst & 511) << 17 | src
__global__ void k_bin(const int* __restrict__ src, const int* __restrict__ dst,
                      int* __restrict__ bcursor, uint* __restrict__ ebuf, int e) {
    __shared__ int lh[256], gb[256], lcur[256];
    int t = threadIdx.x;
    int base = blockIdx.x * 4096;
    int lim = e - base; if (lim > 4096) lim = 4096;
    lh[t] = 0;
    __syncthreads();
    for (int i = t; i < lim; i += 256)
        atomicAdd(&lh[dst[base + i] >> BSH], 1);
    __syncthreads();
    int c = lh[t];
    if (c) gb[t] = atomicAdd(&bcursor[t], c);
    lcur[t] = 0;
    __syncthreads();
    for (int i = t; i < lim; i += 256) {
        int s = src[base + i], d = dst[base + i];
        int b = d >> BSH;
        int p = atomicAdd(&lcur[b], 1);
        ebuf[(size_t)gb[b] + p] = ((uint)(d & 511) << 17) | (uint)s;
    }
}

__global__ void k_bfinal(const uint* __restrict__ ebuf, const int* __restrict__ bbase,
                         int* __restrict__ rp, float* __restrict__ dinv,
                         int* __restrict__ col, int n, int e) {
    __shared__ int hcnt[512], hoff[512], hcur[512];
    int b = blockIdx.x, t = threadIdx.x;
    int node0 = b << BSH;
    int e0 = bbase[b], e1 = bbase[b + 1];
    int m = e1 - e0;
    for (int j = t; j < 512; j += 256) hcnt[j] = 0;
    __syncthreads();
    for (int i = t; i < m; i += 256)
        atomicAdd(&hcnt[ebuf[e0 + i] >> 17], 1);
    __syncthreads();
    if (t == 0) {
        int run = 0;
        for (int j = 0; j < 512; ++j) { hoff[j] = run; run += hcnt[j]; }
    }
    __syncthreads();
    for (int j = t; j < 512; j += 256) {
        int node = node0 + j;
        if (node < n) {
            rp[node] = e0 + hoff[j];
            dinv[node] = rsqrtf((float)(hcnt[j] + 1));
        }
        hcur[j] = hoff[j];
    }
    if (b == 0 && t == 0) rp[n] = e;
    __syncthreads();
    for (int i = t; i < m; i += 256) {
        uint u = ebuf[e0 + i];
        int p = atomicAdd(&hcur[u >> 17], 1);
        col[e0 + p] = (int)(u & 0x1FFFFu);
    }
}

// ---------------- edge records: u32 = dinv[src] top-15 bits | src (17 bits) --

__global__ void k_erec(const int* __restrict__ col, const float* __restrict__ dinv,
                       uint* __restrict__ erec, int e) {
    int i = blockIdx.x * 256 + threadIdx.x;
    if (i < e) {
        int s = col[i];
        uint db = __float_as_uint(dinv[s]);
        erec[i] = ((db + 0x10000u) & 0xFFFE0000u) | (uint)s;  // round-to-nearest 15-bit
    }
}

// ---------------- MFMA GEMM: C = BNReLU(A)[n,128] @ W, half-planar out ------
// MODE 0: A fp32 raw (layer 0). MODE 1: A bf16 + fused BN+ReLU (layers 1,2).
// Output hwh: half h of row r at hwh[(h*NN + r)*64 + (col&63)]  (128 B lines).

template <int MODE>
__global__ __launch_bounds__(256) void k_gemm(
    const void* __restrict__ Ap, const ushort* __restrict__ WT,
    const float* __restrict__ stats, const float* __restrict__ g,
    const float* __restrict__ bt, float inv_n,
    ushort* __restrict__ Cout, int n) {
    __shared__ ushort As[64][136];
    __shared__ ushort Ws[128][136];
    __shared__ float bsc[128], bshf[128];
    int t = threadIdx.x;
    int wave = t >> 6, lane = t & 63;
    int rowBase = blockIdx.x * 64;

    if (MODE == 1) {
        if (t < 128) {
            float mu = stats[t] * inv_n;
            float var = stats[128 + t] * inv_n - mu * mu;
            float sc = g[t] * rsqrtf(var + EPSBN);
            bsc[t] = sc;
            bshf[t] = bt[t] - mu * sc;
        }
        __syncthreads();
    }

    if (MODE == 0) {
        const float* A = (const float*)Ap;
        for (int i = t; i < 64 * 32; i += 256) {
            int r = i >> 5, c4 = i & 31;
            int row = rowBase + r;
            float4 v = make_float4(0.f, 0.f, 0.f, 0.f);
            if (row < n) v = *(const float4*)(A + (size_t)row * H + c4 * 4);
            ushort4 o;
            o.x = f2b(v.x); o.y = f2b(v.y); o.z = f2b(v.z); o.w = f2b(v.w);
            *(ushort4*)(&As[r][c4 * 4]) = o;
        }
    } else {
        const ushort* A = (const ushort*)Ap;
        for (int i = t; i < 64 * 16; i += 256) {
            int r = i >> 4, c8 = i & 15;
            int row = rowBase + r;
            uint4 v = make_uint4(0u, 0u, 0u, 0u);
            if (row < n) v = *(const uint4*)(A + (size_t)row * H + c8 * 8);
            const uint* pv = (const uint*)&v;
            ushort o[8];
#pragma unroll
            for (int j = 0; j < 4; ++j) {
                int f0 = c8 * 8 + 2 * j;
                float v0 = fmaxf(fmaf(blo(pv[j]), bsc[f0], bshf[f0]), 0.f);
                float v1 = fmaxf(fmaf(bhi(pv[j]), bsc[f0 + 1], bshf[f0 + 1]), 0.f);
                o[2 * j] = f2b(v0);
                o[2 * j + 1] = f2b(v1);
            }
            *(uint4*)(&As[r][c8 * 8]) = *(const uint4*)o;
        }
    }
    for (int i = t; i < 128 * 16; i += 256) {
        int j = i >> 4, c8 = i & 15;
        uint4 v = *(const uint4*)(WT + j * H + c8 * 8);
        *(uint4*)(&Ws[j][c8 * 8]) = v;
    }
    __syncthreads();

    int m = lane & 15, qd = lane >> 4;
    f32x4 acc[8];
#pragma unroll
    for (int c = 0; c < 8; ++c) acc[c] = (f32x4){0.f, 0.f, 0.f, 0.f};
#pragma unroll
    for (int kc = 0; kc < 4; ++kc) {
        int kof = kc * 32 + qd * 8;
        s16x8 afrag = *(const s16x8*)(&As[wave * 16 + m][kof]);
#pragma unroll
        for (int c = 0; c < 8; ++c) {
            s16x8 bfrag = *(const s16x8*)(&Ws[c * 16 + m][kof]);
            acc[c] = __builtin_amdgcn_mfma_f32_16x16x32_bf16(afrag, bfrag, acc[c], 0, 0, 0);
        }
    }
#pragma unroll
    for (int c = 0; c < 8; ++c) {
        int colI = c * 16 + m;
        int hh = colI >> 6, cq = colI & 63;
#pragma unroll
        for (int r = 0; r < 4; ++r) {
            int row = rowBase + wave * 16 + qd * 4 + r;
            if (row < n) Cout[((size_t)hh * NN + row) * 64 + cq] = f2b(acc[c][r]);
        }
    }
}

// ---------------- Aggregation + fused BN stats (half-split, per-sub nodes) --
// 8-lane subgroup <-> 128 B half-row (one full cache line, no amplification);
// sub owns whole nodes via LDS cursor; 4-deep per-sub unroll.
// half = blockIdx&1 -> XCDs {0,2,4,6} do half 0, {1,3,5,7} half 1 (12.8 MB/XCD).

__global__ __launch_bounds__(256) void k_agg(
    const ushort* __restrict__ hwh, const int* __restrict__ rp,
    const uint* __restrict__ erec, const float* __restrict__ dinv,
    float* __restrict__ stats, ushort* __restrict__ aggb, int n) {
    __shared__ int cursor;
    __shared__ float lsum[64], lsq[64];
    int t = threadIdx.x;
    int lane = t & 63;
    int sl = lane & 7;       // lane within 8-lane sub
    int sub0 = lane & ~7;    // first lane of sub
    int half = blockIdx.x & 1;
    int nodeBase = (blockIdx.x >> 1) * 256;
    if (t == 0) cursor = 0;
    if (t < 64) { lsum[t] = 0.f; lsq[t] = 0.f; }
    __syncthreads();
    const uint4* hw4 = (const uint4*)hwh;  // half-planar: (half*NN + node)*8 + sl
    uint4* agg4 = (uint4*)aggb;            // interleaved: node*16 + half*8 + sl
    f32x2 ss[4], sq[4];
#pragma unroll
    for (int j = 0; j < 4; ++j) { ss[j] = (f32x2){0.f, 0.f}; sq[j] = (f32x2){0.f, 0.f}; }

    for (;;) {
        int ni = 0;
        if (sl == 0) ni = atomicAdd(&cursor, 1);
        ni = __shfl(ni, sub0);
        int node = nodeBase + ni;
        if (ni >= 256 || node >= n) break;
        float dn = dinv[node];
        f32x2 acc[4];
        {
            uint4 v = hw4[((size_t)half * NN + node) * 8 + sl];
            const uint* pv = (const uint*)&v;
#pragma unroll
            for (int j = 0; j < 4; ++j)
                acc[j] = (f32x2){dn * blo(pv[j]), dn * bhi(pv[j])};
        }
        int p = rp[node], pe = rp[node + 1];
        for (; p < pe; p += 4) {
            int i1 = p + 1 < pe ? p + 1 : pe - 1;
            int i2 = p + 2 < pe ? p + 2 : pe - 1;
            int i3 = p + 3 < pe ? p + 3 : pe - 1;
            uint r0 = erec[p], r1 = erec[i1], r2 = erec[i2], r3 = erec[i3];
            float w0 = __uint_as_float(r0 & 0xFFFE0000u);
            float w1 = (p + 1 < pe) ? __uint_as_float(r1 & 0xFFFE0000u) : 0.f;
            float w2 = (p + 2 < pe) ? __uint_as_float(r2 & 0xFFFE0000u) : 0.f;
            float w3 = (p + 3 < pe) ? __uint_as_float(r3 & 0xFFFE0000u) : 0.f;
            uint4 v0 = hw4[((size_t)half * NN + (r0 & 0x1FFFFu)) * 8 + sl];
            uint4 v1 = hw4[((size_t)half * NN + (r1 & 0x1FFFFu)) * 8 + sl];
            uint4 v2 = hw4[((size_t)half * NN + (r2 & 0x1FFFFu)) * 8 + sl];
            uint4 v3 = hw4[((size_t)half * NN + (r3 & 0x1FFFFu)) * 8 + sl];
            const uint* p0 = (const uint*)&v0;
            const uint* p1 = (const uint*)&v1;
            const uint* p2 = (const uint*)&v2;
            const uint* p3 = (const uint*)&v3;
            f32x2 wv0 = (f32x2){w0, w0}, wv1 = (f32x2){w1, w1};
            f32x2 wv2 = (f32x2){w2, w2}, wv3 = (f32x2){w3, w3};
#pragma unroll
            for (int j = 0; j < 4; ++j) {
                acc[j] = __builtin_elementwise_fma(wv0, (f32x2){blo(p0[j]), bhi(p0[j])}, acc[j]);
                acc[j] = __builtin_elementwise_fma(wv1, (f32x2){blo(p1[j]), bhi(p1[j])}, acc[j]);
                acc[j] = __builtin_elementwise_fma(wv2, (f32x2){blo(p2[j]), bhi(p2[j])}, acc[j]);
                acc[j] = __builtin_elementwise_fma(wv3, (f32x2){blo(p3[j]), bhi(p3[j])}, acc[j]);
            }
        }
        uint4 o;
        uint* po = (uint*)&o;
        f32x2 dn2 = (f32x2){dn, dn};
#pragma unroll
        for (int j = 0; j < 4; ++j) {
            f32x2 ov = dn2 * acc[j];
            ss[j] += ov;
            sq[j] = __builtin_elementwise_fma(ov, ov, sq[j]);
            po[j] = (uint)f2b(ov.x) | ((uint)f2b(ov.y) << 16);
        }
        agg4[(size_t)node * 16 + half * 8 + sl] = o;
    }
#pragma unroll
    for (int j = 0; j < 4; ++j) {
        atomicAdd(&lsum[sl * 8 + 2 * j], ss[j].x);
        atomicAdd(&lsum[sl * 8 + 2 * j + 1], ss[j].y);
        atomicAdd(&lsq[sl * 8 + 2 * j], sq[j].x);
        atomicAdd(&lsq[sl * 8 + 2 * j + 1], sq[j].y);
    }
    __syncthreads();
    if (t < 64) {
        atomicAdd(&stats[half * 64 + t], lsum[t]);
        atomicAdd(&stats[128 + half * 64 + t], lsq[t]);
    }
}

// ---------------- Pooling (BN+ReLU applied inline) ----------------

__global__ void k_gbound(const int* __restrict__ batch, int* __restrict__ gptr, int n) {
    int g = blockIdx.x * 256 + threadIdx.x;
    if (g > GG) return;
    int lo = 0, hi = n;
    while (lo < hi) {
        int mid = (lo + hi) >> 1;
        if (batch[mid] < g) lo = mid + 1; else hi = mid;
    }
    gptr[g] = lo;
}

__global__ void k_pool(const ushort* __restrict__ aggall, const float* __restrict__ statsall,
                       const float* __restrict__ g1, const float* __restrict__ bt1,
                       const float* __restrict__ gc, const float* __restrict__ btc,
                       const int* __restrict__ gptr, float* __restrict__ pooled,
                       float inv_n) {
    int g = blockIdx.x;
    int f = threadIdx.x;  // 384 threads
    int sec = f >> 7, feat = f & 127;
    const float* st = statsall + sec * 256;
    float mu = st[feat] * inv_n;
    float var = st[128 + feat] * inv_n - mu * mu;
    float gm = (sec == 0) ? g1[feat] : gc[(sec - 1) * H + feat];
    float bm = (sec == 0) ? bt1[feat] : btc[(sec - 1) * H + feat];
    float sc = gm * rsqrtf(var + EPSBN);
    float sh = bm - mu * sc;
    const ushort* a = aggall + (size_t)sec * NN * H;
    int r0 = gptr[g], r1 = gptr[g + 1];
    float s = 0.f;
    for (int r = r0; r < r1; ++r)
        s += fmaxf(fmaf(b2f(a[(size_t)r * H + feat]), sc, sh), 0.f);
    float c = (float)(r1 - r0);
    pooled[g * LH + f] = s / fmaxf(c, 1.f);
}

// ---------------- MLP head ----------------

__global__ void k_mlp1(const float* __restrict__ pooled, const float* __restrict__ Wl1,
                       const float* __restrict__ bl1, float* __restrict__ z) {
    __shared__ float row[LH];
    int g = blockIdx.x;
    int j = threadIdx.x;  // 128 threads
    for (int k = j; k < LH; k += H) row[k] = pooled[g * LH + k];
    __syncthreads();
    float acc = bl1[j];
    for (int k = 0; k < LH; ++k) acc += row[k] * Wl1[k * H + j];
    z[g * H + j] = acc;
}

__global__ void k_zstats(const float* __restrict__ z, float* __restrict__ st) {
    int j = threadIdx.x;  // 128 threads, 1 block
    float s = 0.f, q = 0.f;
    for (int g = 0; g < GG; ++g) {
        float v = z[g * H + j];
        s += v;
        q += v * v;
    }
    st[j] = s;
    st[128 + j] = q;
}

__global__ void k_mlp2(const float* __restrict__ z, const float* __restrict__ st,
                       const float* __restrict__ gl, const float* __restrict__ btl,
                       const float* __restrict__ Wl2, const float* __restrict__ bl2,
                       float* __restrict__ out) {
    __shared__ float zn[H];
    __shared__ float logit[CC];
    int g = blockIdx.x;
    int t = threadIdx.x;  // 128 threads
    float mu = st[t] * (1.f / GG);
    float var = st[128 + t] * (1.f / GG) - mu * mu;
    float v = (z[g * H + t] - mu) * rsqrtf(var + EPSBN) * gl[t] + btl[t];
    zn[t] = fmaxf(v, 0.f);
    __syncthreads();
    if (t < CC) {
        float acc = bl2[t];
        for (int k = 0; k < H; ++k) acc += zn[k] * Wl2[k * CC + t];
        logit[t] = acc;
    }
    __syncthreads();
    if (t == 0) {
        float m = -1e30f;
        for (int c = 0; c < CC; ++c) m = fmaxf(m, logit[c]);
        float se = 0.f;
        for (int c = 0; c < CC; ++c) se += expf(logit[c] - m);
        float lse = m + logf(se);
        for (int c = 0; c < CC; ++c) out[g * CC + c] = logit[c] - lse;
    }
}

// ---------------- launch ----------------

extern "C" void kernel_launch(void* const* d_in, const int* in_sizes, int n_in,
                              void* d_out, int out_size, void* d_ws, size_t ws_size,
                              hipStream_t stream) {
    const float* x   = (const float*)d_in[0];
    const int*   ei  = (const int*)d_in[1];
    const int*   bat = (const int*)d_in[2];
    const float* W1  = (const float*)d_in[3];
    const float* g1  = (const float*)d_in[5];
    const float* bt1 = (const float*)d_in[6];
    const float* Wc  = (const float*)d_in[7];
    const float* gc  = (const float*)d_in[9];
    const float* btc = (const float*)d_in[10];
    const float* Wl1 = (const float*)d_in[11];
    const float* bl1 = (const float*)d_in[12];
    const float* gl  = (const float*)d_in[13];
    const float* btl = (const float*)d_in[14];
    const float* Wl2 = (const float*)d_in[15];
    const float* bl2 = (const float*)d_in[16];
    float* out = (float*)d_out;

    const int n = in_sizes[2];
    const int e = in_sizes[1] / 2;
    const int* src = ei;
    const int* dst = ei + e;
    const int nbuck = (n + 511) / 512;  // <= 256
    const float inv_n = 1.0f / (float)n;

    size_t off = 0;
    char* base = (char*)d_ws;
    auto take = [&](size_t nbytes) -> void* {
        void* p = base + off;
        off += (nbytes + 255) & ~(size_t)255;
        return p;
    };
    int*    rp      = (int*)take((size_t)(NN + 1) * 4);
    int*    col     = (int*)take((size_t)NE * 4);
    float*  dinv    = (float*)take((size_t)NN * 4);
    int*    bhist   = (int*)take(1024 + 8);
    int*    bbase   = (int*)take(1024 + 8);
    int*    bcursor = (int*)take(1024 + 8);
    uint*   ebuf    = (uint*)take((size_t)NE * 4);
    uint*   erec    = (uint*)take((size_t)NE * 4);
    float*  stats   = (float*)take(3 * 1024);
    int*    gptr    = (int*)take((size_t)(GG + 1) * 4);
    ushort* WTb     = (ushort*)take((size_t)3 * H * H * 2);
    ushort* hwb     = (ushort*)take((size_t)NN * H * 2);
    ushort* aggb    = (ushort*)take((size_t)3 * NN * H * 2);
    float*  pooled  = (float*)take((size_t)GG * LH * 4);
    float*  z       = (float*)take((size_t)GG * H * 4);
    float*  zst     = (float*)take(1024);

    // ---- weight transpose/convert ----
    k_wt<<<H, H, 0, stream>>>(W1, WTb, 1);
    k_wt<<<2 * H, H, 0, stream>>>(Wc, WTb + (size_t)H * H, 2);

    // ---- bucketed CSR build ----
    hipMemsetAsync(bhist, 0, 1024 + 8, stream);
    k_bhist<<<256, 256, 0, stream>>>(dst, bhist, e, nbuck);
    k_bscan<<<1, 256, 0, stream>>>(bhist, bbase, bcursor, nbuck);
    k_bin<<<(e + 4095) / 4096, 256, 0, stream>>>(src, dst, bcursor, ebuf, e);
    k_bfinal<<<nbuck, 256, 0, stream>>>(ebuf, bbase, rp, dinv, col, n, e);
    k_erec<<<(e + 255) / 256, 256, 0, stream>>>(col, dinv, erec, e);

    // ---- 3 GCN layers (BN+ReLU of layer l-1 fused into layer l's GEMM) ----
    hipMemsetAsync(stats, 0, 3 * 1024, stream);
    for (int l = 0; l < 3; ++l) {
        const ushort* WT = WTb + (size_t)l * H * H;

        if (l == 0) {
            k_gemm<0><<<(n + 63) / 64, 256, 0, stream>>>(
                x, WT, nullptr, nullptr, nullptr, inv_n, hwb, n);
        } else {
            const float* gm  = (l == 1) ? g1 : gc;
            const float* btm = (l == 1) ? bt1 : btc;
            k_gemm<1><<<(n + 63) / 64, 256, 0, stream>>>(
                aggb + (size_t)(l - 1) * NN * H, WT, stats + (size_t)(l - 1) * 256,
                gm, btm, inv_n, hwb, n);
        }
        k_agg<<<((n + 255) / 256) * 2, 256, 0, stream>>>(
            hwb, rp, erec, dinv, stats + (size_t)l * 256, aggb + (size_t)l * NN * H, n);
    }

    // ---- pooling ----
    k_gbound<<<3, 256, 0, stream>>>(bat, gptr, n);
    k_pool<<<GG, LH, 0, stream>>>(aggb, stats, g1, bt1, gc, btc, gptr, pooled, inv_n);

    // ---- MLP head ----
    k_mlp1<<<GG, H, 0, stream>>>(pooled, Wl1, bl1, z);
    k_zstats<<<1, H, 0, stream>>>(z, zst);
    k_mlp2<<<GG, H, 0, stream>>>(z, zst, gl, btl, Wl2, bl2, out);
}

// Round 10
// 537.073 us; speedup vs baseline: 2.1361x; 1.1103x over previous
//
#include <hip/hip_runtime.h>
#include <math.h>

#define NN 100000
#define NE 1600000
#define H 128
#define LH 384
#define GG 512
#define CC 10
#define EPSBN 1e-5f
#define BSH 9  // bucket shift: 512 nodes per bucket

typedef __attribute__((ext_vector_type(4))) float f32x4;
typedef __attribute__((ext_vector_type(2))) float f32x2;
typedef __attribute__((ext_vector_type(8))) short s16x8;
typedef unsigned long long u64;

__device__ inline ushort f2b(float f) {
    uint u = __float_as_uint(f);
    uint r = (u + 0x7FFFu + ((u >> 16) & 1u)) >> 16;
    return (ushort)r;
}
__device__ inline float b2f(ushort b) { return __uint_as_float(((uint)b) << 16); }
__device__ inline float blo(uint v) { return __uint_as_float(v << 16); }
__device__ inline float bhi(uint v) { return __uint_as_float(v & 0xFFFF0000u); }

// ---------------- W transpose + bf16 convert: WT[j*128+k] = W[k*128+j] ------

__global__ void k_wt(const float* __restrict__ W, ushort* __restrict__ WT, int nmat) {
    int mat = blockIdx.x >> 7;
    int k = blockIdx.x & 127;
    int j = threadIdx.x;  // 128 threads
    WT[(size_t)mat * H * H + j * H + k] = f2b(W[(size_t)mat * H * H + k * H + j]);
}

// ---------------- bucketed CSR build ----------------

__global__ void k_bhist(const int* __restrict__ dst, int* __restrict__ bhist,
                        int e, int nbuck) {
    __shared__ int lh[256];
    lh[threadIdx.x] = 0;
    __syncthreads();
    int stride = gridDim.x * 256;
    for (int i = blockIdx.x * 256 + threadIdx.x; i < e; i += stride)
        atomicAdd(&lh[dst[i] >> BSH], 1);
    __syncthreads();
    int v = lh[threadIdx.x];
    if (threadIdx.x < nbuck && v) atomicAdd(&bhist[threadIdx.x], v);
}

__global__ void k_bscan(const int* __restrict__ bhist, int* __restrict__ bbase,
                        int* __restrict__ bcursor, int nbuck) {
    __shared__ int sh[256];
    int t = threadIdx.x;
    int v = (t < nbuck) ? bhist[t] : 0;
    sh[t] = v;
    __syncthreads();
    for (int off = 1; off < 256; off <<= 1) {
        int x = (t >= off) ? sh[t - off] : 0;
        __syncthreads();
        sh[t] += x;
        __syncthreads();
    }
    int run = sh[t] - v;
    if (t < nbuck) { bbase[t] = run; bcursor[t] = run; }
    if (t == nbuck) bbase[t] = run;
    if (t == 255 && nbuck > 255) bbase[nbuck] = sh[255];
}

// block-aggregated scatter: LDS histogram -> 1 global atomic per (block,bucket)
// packed u32 record: (dst & 511) << 17 | src
__global__ void k_bin(const int* __restrict__ src, const int* __restrict__ dst,
                      int* __restrict__ bcursor, uint* __restrict__ ebuf, int e) {
    __shared__ int lh[256], gb[256], lcur[256];
    int t = threadIdx.x;
    int base = blockIdx.x * 4096;
    int lim = e - base; if (lim > 4096) lim = 4096;
    lh[t] = 0;
    __syncthreads();
    for (int i = t; i < lim; i += 256)
        atomicAdd(&lh[dst[base + i] >> BSH], 1);
    __syncthreads();
    int c = lh[t];
    if (c) gb[t] = atomicAdd(&bcursor[t], c);
    lcur[t] = 0;
    __syncthreads();
    for (int i = t; i < lim; i += 256) {
        int s = src[base + i], d = dst[base + i];
        int b = d >> BSH;
        int p = atomicAdd(&lcur[b], 1);
        ebuf[(size_t)gb[b] + p] = ((uint)(d & 511) << 17) | (uint)s;
    }
}

__global__ void k_bfinal(const uint* __restrict__ ebuf, const int* __restrict__ bbase,
                         int* __restrict__ rp, float* __restrict__ dinv,
                         int* __restrict__ col, int n, int e) {
    __shared__ int hcnt[512], hoff[512], hcur[512];
    int b = blockIdx.x, t = threadIdx.x;
    int node0 = b << BSH;
    int e0 = bbase[b], e1 = bbase[b + 1];
    int m = e1 - e0;
    for (int j = t; j < 512; j += 256) hcnt[j] = 0;
    __syncthreads();
    for (int i = t; i < m; i += 256)
        atomicAdd(&hcnt[ebuf[e0 + i] >> 17], 1);
    __syncthreads();
    if (t == 0) {
        int run = 0;
        for (int j = 0; j < 512; ++j) { hoff[j] = run; run += hcnt[j]; }
    }
    __syncthreads();
    for (int j = t; j < 512; j += 256) {
        int node = node0 + j;
        if (node < n) {
            rp[node] = e0 + hoff[j];
            dinv[node] = rsqrtf((float)(hcnt[j] + 1));
        }
        hcur[j] = hoff[j];
    }
    if (b == 0 && t == 0) rp[n] = e;
    __syncthreads();
    for (int i = t; i < m; i += 256) {
        uint u = ebuf[e0 + i];
        int p = atomicAdd(&hcur[u >> 17], 1);
        col[e0 + p] = (int)(u & 0x1FFFFu);
    }
}

// ---------------- edge records: u32 = dinv[src] top-15 bits | src (17 bits) --

__global__ void k_erec(const int* __restrict__ col, const float* __restrict__ dinv,
                       uint* __restrict__ erec, int e) {
    int i = blockIdx.x * 256 + threadIdx.x;
    if (i < e) {
        int s = col[i];
        uint db = __float_as_uint(dinv[s]);
        erec[i] = ((db + 0x10000u) & 0xFFFE0000u) | (uint)s;  // round-to-nearest 15-bit
    }
}

// ---------------- MFMA GEMM: C = BNReLU(A)[n,128] @ W, half-planar out ------
// MODE 0: A fp32 raw (layer 0). MODE 1: A bf16 + fused BN+ReLU (layers 1,2).
// Output hwh: half h of row r at hwh[(h*NN + r)*64 + (col&63)]  (128 B lines).

template <int MODE>
__global__ __launch_bounds__(256) void k_gemm(
    const void* __restrict__ Ap, const ushort* __restrict__ WT,
    const float* __restrict__ stats, const float* __restrict__ g,
    const float* __restrict__ bt, float inv_n,
    ushort* __restrict__ Cout, int n) {
    __shared__ ushort As[64][136];
    __shared__ ushort Ws[128][136];
    __shared__ float bsc[128], bshf[128];
    int t = threadIdx.x;
    int wave = t >> 6, lane = t & 63;
    int rowBase = blockIdx.x * 64;

    if (MODE == 1) {
        if (t < 128) {
            float mu = stats[t] * inv_n;
            float var = stats[128 + t] * inv_n - mu * mu;
            float sc = g[t] * rsqrtf(var + EPSBN);
            bsc[t] = sc;
            bshf[t] = bt[t] - mu * sc;
        }
        __syncthreads();
    }

    if (MODE == 0) {
        const float* A = (const float*)Ap;
        for (int i = t; i < 64 * 32; i += 256) {
            int r = i >> 5, c4 = i & 31;
            int row = rowBase + r;
            float4 v = make_float4(0.f, 0.f, 0.f, 0.f);
            if (row < n) v = *(const float4*)(A + (size_t)row * H + c4 * 4);
            ushort4 o;
            o.x = f2b(v.x); o.y = f2b(v.y); o.z = f2b(v.z); o.w = f2b(v.w);
            *(ushort4*)(&As[r][c4 * 4]) = o;
        }
    } else {
        const ushort* A = (const ushort*)Ap;
        for (int i = t; i < 64 * 16; i += 256) {
            int r = i >> 4, c8 = i & 15;
            int row = rowBase + r;
            uint4 v = make_uint4(0u, 0u, 0u, 0u);
            if (row < n) v = *(const uint4*)(A + (size_t)row * H + c8 * 8);
            const uint* pv = (const uint*)&v;
            ushort o[8];
#pragma unroll
            for (int j = 0; j < 4; ++j) {
                int f0 = c8 * 8 + 2 * j;
                float v0 = fmaxf(fmaf(blo(pv[j]), bsc[f0], bshf[f0]), 0.f);
                float v1 = fmaxf(fmaf(bhi(pv[j]), bsc[f0 + 1], bshf[f0 + 1]), 0.f);
                o[2 * j] = f2b(v0);
                o[2 * j + 1] = f2b(v1);
            }
            *(uint4*)(&As[r][c8 * 8]) = *(const uint4*)o;
        }
    }
    for (int i = t; i < 128 * 16; i += 256) {
        int j = i >> 4, c8 = i & 15;
        uint4 v = *(const uint4*)(WT + j * H + c8 * 8);
        *(uint4*)(&Ws[j][c8 * 8]) = v;
    }
    __syncthreads();

    int m = lane & 15, qd = lane >> 4;
    f32x4 acc[8];
#pragma unroll
    for (int c = 0; c < 8; ++c) acc[c] = (f32x4){0.f, 0.f, 0.f, 0.f};
#pragma unroll
    for (int kc = 0; kc < 4; ++kc) {
        int kof = kc * 32 + qd * 8;
        s16x8 afrag = *(const s16x8*)(&As[wave * 16 + m][kof]);
#pragma unroll
        for (int c = 0; c < 8; ++c) {
            s16x8 bfrag = *(const s16x8*)(&Ws[c * 16 + m][kof]);
            acc[c] = __builtin_amdgcn_mfma_f32_16x16x32_bf16(afrag, bfrag, acc[c], 0, 0, 0);
        }
    }
#pragma unroll
    for (int c = 0; c < 8; ++c) {
        int colI = c * 16 + m;
        int hh = colI >> 6, cq = colI & 63;
#pragma unroll
        for (int r = 0; r < 4; ++r) {
            int row = rowBase + wave * 16 + qd * 4 + r;
            if (row < n) Cout[((size_t)hh * NN + row) * 64 + cq] = f2b(acc[c][r]);
        }
    }
}

// ---------------- Aggregation + fused BN stats (half-split, per-sub nodes) --

__global__ __launch_bounds__(256) void k_agg(
    const ushort* __restrict__ hwh, const int* __restrict__ rp,
    const uint* __restrict__ erec, const float* __restrict__ dinv,
    float* __restrict__ stats, ushort* __restrict__ aggb, int n) {
    __shared__ int cursor;
    __shared__ float lsum[64], lsq[64];
    int t = threadIdx.x;
    int lane = t & 63;
    int sl = lane & 7;       // lane within 8-lane sub
    int sub0 = lane & ~7;    // first lane of sub
    int half = blockIdx.x & 1;
    int nodeBase = (blockIdx.x >> 1) * 256;
    if (t == 0) cursor = 0;
    if (t < 64) { lsum[t] = 0.f; lsq[t] = 0.f; }
    __syncthreads();
    const uint4* hw4 = (const uint4*)hwh;  // half-planar: (half*NN + node)*8 + sl
    uint4* agg4 = (uint4*)aggb;            // interleaved: node*16 + half*8 + sl
    f32x2 ss[4], sq[4];
#pragma unroll
    for (int j = 0; j < 4; ++j) { ss[j] = (f32x2){0.f, 0.f}; sq[j] = (f32x2){0.f, 0.f}; }

    for (;;) {
        int ni = 0;
        if (sl == 0) ni = atomicAdd(&cursor, 1);
        ni = __shfl(ni, sub0);
        int node = nodeBase + ni;
        if (ni >= 256 || node >= n) break;
        float dn = dinv[node];
        f32x2 acc[4];
        {
            uint4 v = hw4[((size_t)half * NN + node) * 8 + sl];
            const uint* pv = (const uint*)&v;
#pragma unroll
            for (int j = 0; j < 4; ++j)
                acc[j] = (f32x2){dn * blo(pv[j]), dn * bhi(pv[j])};
        }
        int p = rp[node], pe = rp[node + 1];
        for (; p < pe; p += 4) {
            int i1 = p + 1 < pe ? p + 1 : pe - 1;
            int i2 = p + 2 < pe ? p + 2 : pe - 1;
            int i3 = p + 3 < pe ? p + 3 : pe - 1;
            uint r0 = erec[p], r1 = erec[i1], r2 = erec[i2], r3 = erec[i3];
            float w0 = __uint_as_float(r0 & 0xFFFE0000u);
            float w1 = (p + 1 < pe) ? __uint_as_float(r1 & 0xFFFE0000u) : 0.f;
            float w2 = (p + 2 < pe) ? __uint_as_float(r2 & 0xFFFE0000u) : 0.f;
            float w3 = (p + 3 < pe) ? __uint_as_float(r3 & 0xFFFE0000u) : 0.f;
            uint4 v0 = hw4[((size_t)half * NN + (r0 & 0x1FFFFu)) * 8 + sl];
            uint4 v1 = hw4[((size_t)half * NN + (r1 & 0x1FFFFu)) * 8 + sl];
            uint4 v2 = hw4[((size_t)half * NN + (r2 & 0x1FFFFu)) * 8 + sl];
            uint4 v3 = hw4[((size_t)half * NN + (r3 & 0x1FFFFu)) * 8 + sl];
            const uint* p0 = (const uint*)&v0;
            const uint* p1 = (const uint*)&v1;
            const uint* p2 = (const uint*)&v2;
            const uint* p3 = (const uint*)&v3;
            f32x2 wv0 = (f32x2){w0, w0}, wv1 = (f32x2){w1, w1};
            f32x2 wv2 = (f32x2){w2, w2}, wv3 = (f32x2){w3, w3};
#pragma unroll
            for (int j = 0; j < 4; ++j) {
                acc[j] = __builtin_elementwise_fma(wv0, (f32x2){blo(p0[j]), bhi(p0[j])}, acc[j]);
                acc[j] = __builtin_elementwise_fma(wv1, (f32x2){blo(p1[j]), bhi(p1[j])}, acc[j]);
                acc[j] = __builtin_elementwise_fma(wv2, (f32x2){blo(p2[j]), bhi(p2[j])}, acc[j]);
                acc[j] = __builtin_elementwise_fma(wv3, (f32x2){blo(p3[j]), bhi(p3[j])}, acc[j]);
            }
        }
        uint4 o;
        uint* po = (uint*)&o;
        f32x2 dn2 = (f32x2){dn, dn};
#pragma unroll
        for (int j = 0; j < 4; ++j) {
            f32x2 ov = dn2 * acc[j];
            ss[j] += ov;
            sq[j] = __builtin_elementwise_fma(ov, ov, sq[j]);
            po[j] = (uint)f2b(ov.x) | ((uint)f2b(ov.y) << 16);
        }
        agg4[(size_t)node * 16 + half * 8 + sl] = o;
    }
#pragma unroll
    for (int j = 0; j < 4; ++j) {
        atomicAdd(&lsum[sl * 8 + 2 * j], ss[j].x);
        atomicAdd(&lsum[sl * 8 + 2 * j + 1], ss[j].y);
        atomicAdd(&lsq[sl * 8 + 2 * j], sq[j].x);
        atomicAdd(&lsq[sl * 8 + 2 * j + 1], sq[j].y);
    }
    __syncthreads();
    if (t < 64) {
        atomicAdd(&stats[half * 64 + t], lsum[t]);
        atomicAdd(&stats[128 + half * 64 + t], lsq[t]);
    }
}

// ---------------- Pooling (BN+ReLU inline, vectorized) ----------------
// grid (512 groups, 6 slices of 64 feats); block 256 = 32 row-lanes x 8 chunks.
// Each thread: uint4 (8 bf16) per row, rows strided by 32; LDS reduce.

__global__ void k_gbound(const int* __restrict__ batch, int* __restrict__ gptr, int n) {
    int g = blockIdx.x * 256 + threadIdx.x;
    if (g > GG) return;
    int lo = 0, hi = n;
    while (lo < hi) {
        int mid = (lo + hi) >> 1;
        if (batch[mid] < g) lo = mid + 1; else hi = mid;
    }
    gptr[g] = lo;
}

__global__ __launch_bounds__(256) void k_pool(
    const ushort* __restrict__ aggall, const float* __restrict__ statsall,
    const float* __restrict__ g1, const float* __restrict__ bt1,
    const float* __restrict__ gc, const float* __restrict__ btc,
    const int* __restrict__ gptr, float* __restrict__ pooled, float inv_n) {
    __shared__ float bsc[64], bshf[64];
    __shared__ float red[32][64];
    int g = blockIdx.x;
    int s = blockIdx.y;              // feature slice: 64 feats
    int sec = s >> 1;                // section (layer) 0..2
    int c = threadIdx.x & 7;         // uint4 chunk within slice
    int rg = threadIdx.x >> 3;       // row lane 0..31
    int t = threadIdx.x;

    if (t < 64) {
        int feat = (s & 1) * 64 + t;  // feature within section (0..127)
        const float* st = statsall + sec * 256;
        float mu = st[feat] * inv_n;
        float var = st[128 + feat] * inv_n - mu * mu;
        float gm = (sec == 0) ? g1[feat] : gc[(sec - 1) * H + feat];
        float bm = (sec == 0) ? bt1[feat] : btc[(sec - 1) * H + feat];
        float sc = gm * rsqrtf(var + EPSBN);
        bsc[t] = sc;
        bshf[t] = bm - mu * sc;
    }
    __syncthreads();

    int r0 = gptr[g], r1 = gptr[g + 1];
    const uint4* a4 = (const uint4*)aggall;
    size_t secBase = (size_t)sec * NN * 16;
    int cOff = (s & 1) * 8 + c;
    float acc[8];
#pragma unroll
    for (int j = 0; j < 8; ++j) acc[j] = 0.f;
    for (int r = r0 + rg; r < r1; r += 32) {
        uint4 v = a4[secBase + (size_t)r * 16 + cOff];
        const uint* pv = (const uint*)&v;
#pragma unroll
        for (int j = 0; j < 4; ++j) {
            int f0 = c * 8 + 2 * j;
            acc[2 * j]     += fmaxf(fmaf(blo(pv[j]), bsc[f0], bshf[f0]), 0.f);
            acc[2 * j + 1] += fmaxf(fmaf(bhi(pv[j]), bsc[f0 + 1], bshf[f0 + 1]), 0.f);
        }
    }
#pragma unroll
    for (int j = 0; j < 8; ++j) red[rg][c * 8 + j] = acc[j];
    __syncthreads();
    if (t < 64) {
        float sum = 0.f;
#pragma unroll
        for (int rr = 0; rr < 32; ++rr) sum += red[rr][t];
        float cnt = (float)(r1 - r0);
        pooled[g * LH + s * 64 + t] = sum / fmaxf(cnt, 1.f);
    }
}

// ---------------- MLP head ----------------

__global__ void k_mlp1(const float* __restrict__ pooled, const float* __restrict__ Wl1,
                       const float* __restrict__ bl1, float* __restrict__ z) {
    __shared__ float row[LH];
    int g = blockIdx.x;
    int j = threadIdx.x;  // 128 threads
    for (int k = j; k < LH; k += H) row[k] = pooled[g * LH + k];
    __syncthreads();
    float acc = bl1[j];
    for (int k = 0; k < LH; ++k) acc += row[k] * Wl1[k * H + j];
    z[g * H + j] = acc;
}

__global__ void k_zstats(const float* __restrict__ z, float* __restrict__ st) {
    int j = threadIdx.x;  // 128 threads, 1 block
    float s = 0.f, q = 0.f;
    for (int g = 0; g < GG; ++g) {
        float v = z[g * H + j];
        s += v;
        q += v * v;
    }
    st[j] = s;
    st[128 + j] = q;
}

__global__ void k_mlp2(const float* __restrict__ z, const float* __restrict__ st,
                       const float* __restrict__ gl, const float* __restrict__ btl,
                       const float* __restrict__ Wl2, const float* __restrict__ bl2,
                       float* __restrict__ out) {
    __shared__ float zn[H];
    __shared__ float logit[CC];
    int g = blockIdx.x;
    int t = threadIdx.x;  // 128 threads
    float mu = st[t] * (1.f / GG);
    float var = st[128 + t] * (1.f / GG) - mu * mu;
    float v = (z[g * H + t] - mu) * rsqrtf(var + EPSBN) * gl[t] + btl[t];
    zn[t] = fmaxf(v, 0.f);
    __syncthreads();
    if (t < CC) {
        float acc = bl2[t];
        for (int k = 0; k < H; ++k) acc += zn[k] * Wl2[k * CC + t];
        logit[t] = acc;
    }
    __syncthreads();
    if (t == 0) {
        float m = -1e30f;
        for (int c = 0; c < CC; ++c) m = fmaxf(m, logit[c]);
        float se = 0.f;
        for (int c = 0; c < CC; ++c) se += expf(logit[c] - m);
        float lse = m + logf(se);
        for (int c = 0; c < CC; ++c) out[g * CC + c] = logit[c] - lse;
    }
}

// ---------------- launch ----------------

extern "C" void kernel_launch(void* const* d_in, const int* in_sizes, int n_in,
                              void* d_out, int out_size, void* d_ws, size_t ws_size,
                              hipStream_t stream) {
    const float* x   = (const float*)d_in[0];
    const int*   ei  = (const int*)d_in[1];
    const int*   bat = (const int*)d_in[2];
    const float* W1  = (const float*)d_in[3];
    const float* g1  = (const float*)d_in[5];
    const float* bt1 = (const float*)d_in[6];
    const float* Wc  = (const float*)d_in[7];
    const float* gc  = (const float*)d_in[9];
    const float* btc = (const float*)d_in[10];
    const float* Wl1 = (const float*)d_in[11];
    const float* bl1 = (const float*)d_in[12];
    const float* gl  = (const float*)d_in[13];
    const float* btl = (const float*)d_in[14];
    const float* Wl2 = (const float*)d_in[15];
    const float* bl2 = (const float*)d_in[16];
    float* out = (float*)d_out;

    const int n = in_sizes[2];
    const int e = in_sizes[1] / 2;
    const int* src = ei;
    const int* dst = ei + e;
    const int nbuck = (n + 511) / 512;  // <= 256
    const float inv_n = 1.0f / (float)n;

    size_t off = 0;
    char* base = (char*)d_ws;
    auto take = [&](size_t nbytes) -> void* {
        void* p = base + off;
        off += (nbytes + 255) & ~(size_t)255;
        return p;
    };
    int*    rp      = (int*)take((size_t)(NN + 1) * 4);
    int*    col     = (int*)take((size_t)NE * 4);
    float*  dinv    = (float*)take((size_t)NN * 4);
    int*    bhist   = (int*)take(1024 + 8);
    int*    bbase   = (int*)take(1024 + 8);
    int*    bcursor = (int*)take(1024 + 8);
    uint*   ebuf    = (uint*)take((size_t)NE * 4);
    uint*   erec    = (uint*)take((size_t)NE * 4);
    float*  stats   = (float*)take(3 * 1024);
    int*    gptr    = (int*)take((size_t)(GG + 1) * 4);
    ushort* WTb     = (ushort*)take((size_t)3 * H * H * 2);
    ushort* hwb     = (ushort*)take((size_t)NN * H * 2);
    ushort* aggb    = (ushort*)take((size_t)3 * NN * H * 2);
    float*  pooled  = (float*)take((size_t)GG * LH * 4);
    float*  z       = (float*)take((size_t)GG * H * 4);
    float*  zst     = (float*)take(1024);

    // ---- weight transpose/convert ----
    k_wt<<<H, H, 0, stream>>>(W1, WTb, 1);
    k_wt<<<2 * H, H, 0, stream>>>(Wc, WTb + (size_t)H * H, 2);

    // ---- bucketed CSR build ----
    hipMemsetAsync(bhist, 0, 1024 + 8, stream);
    k_bhist<<<256, 256, 0, stream>>>(dst, bhist, e, nbuck);
    k_bscan<<<1, 256, 0, stream>>>(bhist, bbase, bcursor, nbuck);
    k_bin<<<(e + 4095) / 4096, 256, 0, stream>>>(src, dst, bcursor, ebuf, e);
    k_bfinal<<<nbuck, 256, 0, stream>>>(ebuf, bbase, rp, dinv, col, n, e);
    k_erec<<<(e + 255) / 256, 256, 0, stream>>>(col, dinv, erec, e);

    // ---- 3 GCN layers (BN+ReLU of layer l-1 fused into layer l's GEMM) ----
    hipMemsetAsync(stats, 0, 3 * 1024, stream);
    for (int l = 0; l < 3; ++l) {
        const ushort* WT = WTb + (size_t)l * H * H;

        if (l == 0) {
            k_gemm<0><<<(n + 63) / 64, 256, 0, stream>>>(
                x, WT, nullptr, nullptr, nullptr, inv_n, hwb, n);
        } else {
            const float* gm  = (l == 1) ? g1 : gc;
            const float* btm = (l == 1) ? bt1 : btc;
            k_gemm<1><<<(n + 63) / 64, 256, 0, stream>>>(
                aggb + (size_t)(l - 1) * NN * H, WT, stats + (size_t)(l - 1) * 256,
                gm, btm, inv_n, hwb, n);
        }
        k_agg<<<((n + 255) / 256) * 2, 256, 0, stream>>>(
            hwb, rp, erec, dinv, stats + (size_t)l * 256, aggb + (size_t)l * NN * H, n);
    }

    // ---- pooling ----
    k_gbound<<<3, 256, 0, stream>>>(bat, gptr, n);
    {
        dim3 pg(GG, 6);
        k_pool<<<pg, 256, 0, stream>>>(aggb, stats, g1, bt1, gc, btc, gptr, pooled, inv_n);
    }

    // ---- MLP head ----
    k_mlp1<<<GG, H, 0, stream>>>(pooled, Wl1, bl1, z);
    k_zstats<<<1, H, 0, stream>>>(z, zst);
    k_mlp2<<<GG, H, 0, stream>>>(z, zst, gl, btl, Wl2, bl2, out);
}